// Round 5
// baseline (882.177 us; speedup 1.0000x reference)
//
#include <hip/hip_runtime.h>
#include <cstdint>
#include <cstddef>

typedef __bf16 bf16x8 __attribute__((ext_vector_type(8)));
typedef float f32x4 __attribute__((ext_vector_type(4)));

__device__ __forceinline__ float bf2f(unsigned short u){
  unsigned int x = ((unsigned int)u) << 16;
  return __builtin_bit_cast(float, x);
}
__device__ __forceinline__ unsigned short f2bf(float f){
  unsigned int x = __builtin_bit_cast(unsigned int, f);
  x += 0x7fffu + ((x >> 16) & 1u);
  return (unsigned short)(x >> 16);
}

// ---------------- dtype detect + canonicalize ----------------
__global__ void k_detect(const unsigned short* __restrict__ xs, int* __restrict__ flag){
  __shared__ int found;
  if (threadIdx.x == 0) found = 0;
  __syncthreads();
  for (int i = threadIdx.x; i < 4096; i += 256){
    unsigned short u = xs[i];
    int expo = (u >> 7) & 0xFF;
    if (expo >= 0xC0) atomicOr(&found, 1);
  }
  __syncthreads();
  if (threadIdx.x == 0) flag[0] = found;
}

struct ParamTab {
  const void* src[17];
  float*      dst[17];
  int         n[17];
};
__global__ void k_canon_params(ParamTab t, const int* __restrict__ flag){
  int b = blockIdx.x, i = threadIdx.x;
  if (i < t.n[b]){
    t.dst[b][i] = flag[0] ? ((const float*)t.src[b])[i]
                          : bf2f(((const unsigned short*)t.src[b])[i]);
  }
}

__global__ void k_canon_f32(const void* __restrict__ src, float* __restrict__ dst,
                            int n, const int* __restrict__ flag){
  int i = blockIdx.x*256 + threadIdx.x;
  if (i < n){
    dst[i] = flag[0] ? ((const float*)src)[i]
                     : bf2f(((const unsigned short*)src)[i]);
  }
}

__global__ void k_canon_bf16(const void* __restrict__ src, unsigned short* __restrict__ dst,
                             int n, const int* __restrict__ flag){
  int i = blockIdx.x*256 + threadIdx.x;
  if (i < n){
    dst[i] = flag[0] ? f2bf(((const float*)src)[i])
                     : ((const unsigned short*)src)[i];
  }
}

struct WTab {
  const void* src[6];
  unsigned short* dst[6];
  int M[6];
};
__global__ void k_canonT(WTab t, const int* __restrict__ flag){
  int b = blockIdx.y;
  int M = t.M[b];
  int idx = blockIdx.x*256 + threadIdx.x;
  if (idx < 128*M){
    int k = idx / M, m = idx % M;
    unsigned short v = flag[0] ? f2bf(((const float*)t.src[b])[idx])
                               : ((const unsigned short*)t.src[b])[idx];
    t.dst[b][m*128 + k] = v;
  }
}

// ---------------- graph build ----------------

__global__ void k_hist(const int* __restrict__ ei, const float* __restrict__ ewc,
                       int* __restrict__ cnt, float* __restrict__ wsum, int E, int n){
  int e = blockIdx.x*256 + threadIdx.x;
  if (e < E){
    int d = ei[E + e];
    if ((unsigned)d < (unsigned)n){
      atomicAdd(&cnt[d], 1);
      atomicAdd(&wsum[d], ewc[e]);
    }
  }
}

__global__ void k_scan1(const int* __restrict__ cnt, int* __restrict__ bsum, int n){
  int i = blockIdx.x*256 + threadIdx.x;
  int lane = threadIdx.x & 63, w = threadIdx.x >> 6;
  int v = (i < n) ? cnt[i] + 1 : 0;
  for (int off = 32; off; off >>= 1) v += __shfl_down(v, off);
  __shared__ int ws[4];
  if (lane == 0) ws[w] = v;
  __syncthreads();
  if (threadIdx.x == 0) bsum[blockIdx.x] = ws[0] + ws[1] + ws[2] + ws[3];
}

__global__ void k_scan2(const int* __restrict__ bsum, int* __restrict__ boff, int B){
  int tid = threadIdx.x, lane = tid & 63, w = tid >> 6;
  __shared__ int ws[16];
  int v = (tid < B) ? bsum[tid] : 0;
  int sv = v;
  for (int off = 1; off < 64; off <<= 1){
    int t = __shfl_up(sv, off);
    if (lane >= off) sv += t;
  }
  if (lane == 63) ws[w] = sv;
  __syncthreads();
  if (tid == 0){
    int acc = 0;
    for (int k = 0; k < 16; k++){ int t = ws[k]; ws[k] = acc; acc += t; }
  }
  __syncthreads();
  if (tid < B) boff[tid] = ws[w] + sv - v;
}

__global__ void k_scan3(const int* __restrict__ cnt, const int* __restrict__ boff,
                        int* __restrict__ rowptr, int n){
  int b = blockIdx.x, tid = threadIdx.x;
  int i = b*256 + tid;
  int lane = tid & 63, w = tid >> 6;
  __shared__ int ws[4];
  int v = (i < n) ? cnt[i] + 1 : 0;
  int sv = v;
  for (int off = 1; off < 64; off <<= 1){
    int t = __shfl_up(sv, off);
    if (lane >= off) sv += t;
  }
  if (lane == 63) ws[w] = sv;
  __syncthreads();
  if (tid == 0){
    int acc = 0;
    for (int k = 0; k < 4; k++){ int t = ws[k]; ws[k] = acc; acc += t; }
  }
  __syncthreads();
  if (i < n) rowptr[i + 1] = boff[b] + ws[w] + sv;
  if (i == 0) rowptr[0] = 0;
}

__global__ void k_self(const int* __restrict__ rowptr, const int* __restrict__ cnt,
                       const float* __restrict__ wsum, int* __restrict__ fill,
                       int* __restrict__ csr_src, float* __restrict__ csr_w, int n, int ET){
  int i = blockIdx.x*256 + threadIdx.x;
  if (i < n){
    fill[i] = rowptr[i];
    int slot = rowptr[i+1] - 1;
    if ((unsigned)slot < (unsigned)ET){
      csr_src[slot] = i;
      csr_w[slot] = wsum[i] / fmaxf((float)cnt[i], 1.0f);
    }
  }
}

__global__ void k_scatter(const int* __restrict__ ei, const float* __restrict__ ewc,
                          int* __restrict__ fill, int* __restrict__ csr_src,
                          float* __restrict__ csr_w, int E, int n, int ET){
  int e = blockIdx.x*256 + threadIdx.x;
  if (e < E){
    int s = ei[e], d = ei[E + e];
    if ((unsigned)d < (unsigned)n){
      int pos = atomicAdd(&fill[d], 1);
      if ((unsigned)pos < (unsigned)ET){
        csr_src[pos] = s;
        csr_w[pos] = ewc[e];
      }
    }
  }
}

// ---------------- fused xl/xr GEMM (bf16 MFMA, f32 out) ----------------

__global__ __launch_bounds__(64) void k_gemm(
  const unsigned short* __restrict__ A,
  const unsigned short* __restrict__ WTl, const unsigned short* __restrict__ WTr,
  const float* __restrict__ bl, const float* __restrict__ br,
  float* __restrict__ outL, float* __restrict__ outR,
  int nrows, int ncols)
{
  int lane = threadIdx.x;
  int q = lane >> 4, rr = lane & 15;
  int r0 = blockIdx.x * 64;
  int per = ncols >> 6;
  int slice = blockIdx.y;
  bool isR = slice >= per;
  const unsigned short* WT  = isR ? WTr : WTl;
  const float* bia          = isR ? br  : bl;
  float* out                = isR ? outR : outL;
  int n0 = (slice - (isR ? per : 0)) * 64;

  f32x4 acc[4][4];
  for (int a = 0; a < 4; a++)
    for (int b = 0; b < 4; b++)
      acc[a][b] = (f32x4){0.f, 0.f, 0.f, 0.f};

  for (int kc = 0; kc < 4; kc++){
    bf16x8 af[4], bfr[4];
    for (int rt = 0; rt < 4; rt++){
      int row = r0 + rt*16 + rr;
      if (row >= nrows) row = nrows - 1;
      af[rt] = *(const bf16x8*)(A + (size_t)row*128 + kc*32 + q*8);
    }
    for (int ct = 0; ct < 4; ct++){
      bfr[ct] = *(const bf16x8*)(WT + (size_t)(n0 + ct*16 + rr)*128 + kc*32 + q*8);
    }
    for (int rt = 0; rt < 4; rt++)
      for (int ct = 0; ct < 4; ct++)
        acc[rt][ct] = __builtin_amdgcn_mfma_f32_16x16x32_bf16(af[rt], bfr[ct], acc[rt][ct], 0, 0, 0);
  }

  for (int ct = 0; ct < 4; ct++){
    int col = n0 + ct*16 + rr;
    float bv = bia[col];
    for (int rt = 0; rt < 4; rt++){
      for (int t = 0; t < 4; t++){
        int row = r0 + rt*16 + q*4 + t;
        if (row < nrows)
          out[(size_t)row*ncols + col] = acc[rt][ct][t] + bv;
      }
    }
  }
}

// ---------------- fused edge scoring + online-softmax aggregation ----------------
// Two-phase per-node wave. Phase A: lane=edge computes its own score, NO per-edge
// shuffles (only a per-chunk max butterfly). Phase B: lane=channel, per edge one
// broadcast ds_read + coalesced row read. Softmax denominator accumulated in B.

__global__ __launch_bounds__(256) void k_edge128(
  const float* __restrict__ xl, const float* __restrict__ xr,
  const int* __restrict__ rowptr, const int* __restrict__ csr_src, const float* __restrict__ csr_w,
  const float* __restrict__ We, const float* __restrict__ att,
  const float* __restrict__ bias, unsigned short* __restrict__ out, int n, int ET)
{
  __shared__ float4 sEx[4][64];
  int wid = threadIdx.x >> 6;
  int lane = threadIdx.x & 63;
  int node = blockIdx.x*4 + wid;
  if (node >= n) return;
  int ch = lane*2;
  int head = lane >> 4;
  int beg = rowptr[node], end = rowptr[node+1];
  if (beg < 0) beg = 0;
  if (end > ET) end = ET;
  const float* xrrow = xr + (size_t)node*128;
  float m0=-1e30f, m1=-1e30f, m2=-1e30f, m3=-1e30f;
  float l = 0.f, a0 = 0.f, a1 = 0.f;

  for (int base = beg; base < end; base += 64){
    int cnt = end - base; if (cnt > 64) cnt = 64;
    int idx = base + lane;
    bool act = idx < end;
    int s = act ? csr_src[idx] : 0;
    float w = act ? csr_w[idx] : 0.f;
    if ((unsigned)s >= (unsigned)n) s = 0;

    // ---- phase A: per-lane scores for 4 heads over 128 channels ----
    float p0 = 0.f, p1 = 0.f, p2 = 0.f, p3 = 0.f;
    const float* xlrow = xl + (size_t)s*128;
    #pragma unroll 8
    for (int k = 0; k < 32; k++){
      float4 xv = ((const float4*)xlrow)[k];
      float4 rv = ((const float4*)xrrow)[k];
      float4 wv = ((const float4*)We)[k];
      float4 av = ((const float4*)att)[k];
      float t0 = xv.x + rv.x + w*wv.x; t0 = t0 > 0.f ? t0 : 0.2f*t0;
      float t1 = xv.y + rv.y + w*wv.y; t1 = t1 > 0.f ? t1 : 0.2f*t1;
      float t2 = xv.z + rv.z + w*wv.z; t2 = t2 > 0.f ? t2 : 0.2f*t2;
      float t3 = xv.w + rv.w + w*wv.w; t3 = t3 > 0.f ? t3 : 0.2f*t3;
      float d = t0*av.x + t1*av.y + t2*av.z + t3*av.w;
      int h = k >> 3;
      if (h == 0) p0 += d; else if (h == 1) p1 += d;
      else if (h == 2) p2 += d; else p3 += d;
    }
    if (!act){ p0 = p1 = p2 = p3 = -1e30f; }

    // per-chunk max butterfly (only DS cost that scales with chunks, not edges)
    float c0 = p0, c1 = p1, c2 = p2, c3 = p3;
    for (int d = 1; d < 64; d <<= 1){
      c0 = fmaxf(c0, __shfl_xor(c0, d));
      c1 = fmaxf(c1, __shfl_xor(c1, d));
      c2 = fmaxf(c2, __shfl_xor(c2, d));
      c3 = fmaxf(c3, __shfl_xor(c3, d));
    }
    float n0 = fmaxf(m0, c0), n1 = fmaxf(m1, c1);
    float n2 = fmaxf(m2, c2), n3 = fmaxf(m3, c3);
    float4 ex;
    ex.x = __expf(p0 - n0); ex.y = __expf(p1 - n1);
    ex.z = __expf(p2 - n2); ex.w = __expf(p3 - n3);
    sEx[wid][lane] = ex;
    // rescale accumulators by this lane's head scale
    float s0 = __expf(m0 - n0), s1 = __expf(m1 - n1);
    float s2 = __expf(m2 - n2), s3 = __expf(m3 - n3);
    float sc = head < 2 ? (head == 0 ? s0 : s1) : (head == 2 ? s2 : s3);
    a0 *= sc; a1 *= sc; l *= sc;
    m0 = n0; m1 = n1; m2 = n2; m3 = n3;

    // ---- phase B: lane=channel aggregation; coalesced row reads ----
    for (int e = 0; e < cnt; e++){
      float4 exv = sEx[wid][e];                       // broadcast ds_read_b128
      float exh = head < 2 ? (head == 0 ? exv.x : exv.y)
                           : (head == 2 ? exv.z : exv.w);
      int s_e = csr_src[base + e];                    // wave-uniform, L1 hit
      if ((unsigned)s_e >= (unsigned)n) s_e = 0;
      float2 xv = *(const float2*)(xl + (size_t)s_e*128 + ch);  // coalesced 512B row
      l  += exh;
      a0 += exh * xv.x;
      a1 += exh * xv.y;
    }
  }
  float inv = 1.0f / (l + 1e-16f);
  float o0 = a0*inv + bias[ch];
  float o1 = a1*inv + bias[ch+1];
  o0 = o0 > 0.f ? o0 : (__expf(o0) - 1.0f);   // ELU (layers 0,1)
  o1 = o1 > 0.f ? o1 : (__expf(o1) - 1.0f);
  unsigned int packed = (unsigned int)f2bf(o0) | ((unsigned int)f2bf(o1) << 16);
  *(unsigned int*)(out + (size_t)node*128 + ch) = packed;
}

// OUT=64, 1 head: same two-phase structure.
__global__ __launch_bounds__(256) void k_edge64(
  const float* __restrict__ xl, const float* __restrict__ xr,
  const int* __restrict__ rowptr, const int* __restrict__ csr_src, const float* __restrict__ csr_w,
  const float* __restrict__ We, const float* __restrict__ att,
  const float* __restrict__ bias, void* __restrict__ out, int n, int ET,
  const int* __restrict__ flag)
{
  __shared__ float sEx[4][64];
  int wid = threadIdx.x >> 6;
  int lane = threadIdx.x & 63;
  int node = blockIdx.x*4 + wid;
  if (node >= n) return;
  int beg = rowptr[node], end = rowptr[node+1];
  if (beg < 0) beg = 0;
  if (end > ET) end = ET;
  const float* xrrow = xr + (size_t)node*64;
  float m = -1e30f, l = 0.f, a0 = 0.f;

  for (int base = beg; base < end; base += 64){
    int cnt = end - base; if (cnt > 64) cnt = 64;
    int idx = base + lane;
    bool act = idx < end;
    int s = act ? csr_src[idx] : 0;
    float w = act ? csr_w[idx] : 0.f;
    if ((unsigned)s >= (unsigned)n) s = 0;

    // ---- phase A ----
    float p = 0.f;
    const float* xlrow = xl + (size_t)s*64;
    #pragma unroll 8
    for (int k = 0; k < 16; k++){
      float4 xv = ((const float4*)xlrow)[k];
      float4 rv = ((const float4*)xrrow)[k];
      float4 wv = ((const float4*)We)[k];
      float4 av = ((const float4*)att)[k];
      float t0 = xv.x + rv.x + w*wv.x; t0 = t0 > 0.f ? t0 : 0.2f*t0;
      float t1 = xv.y + rv.y + w*wv.y; t1 = t1 > 0.f ? t1 : 0.2f*t1;
      float t2 = xv.z + rv.z + w*wv.z; t2 = t2 > 0.f ? t2 : 0.2f*t2;
      float t3 = xv.w + rv.w + w*wv.w; t3 = t3 > 0.f ? t3 : 0.2f*t3;
      p += t0*av.x + t1*av.y + t2*av.z + t3*av.w;
    }
    if (!act) p = -1e30f;

    float c = p;
    for (int d = 1; d < 64; d <<= 1) c = fmaxf(c, __shfl_xor(c, d));
    float nm = fmaxf(m, c);
    float ex = __expf(p - nm);
    sEx[wid][lane] = ex;
    float sc = __expf(m - nm);
    a0 *= sc; l *= sc;
    m = nm;

    // ---- phase B ----
    for (int e = 0; e < cnt; e++){
      float ex_e = sEx[wid][e];                       // broadcast ds_read
      int s_e = csr_src[base + e];                    // wave-uniform, L1
      if ((unsigned)s_e >= (unsigned)n) s_e = 0;
      float x = xl[(size_t)s_e*64 + lane];            // coalesced 256B row
      l  += ex_e;
      a0 += ex_e * x;
    }
  }
  float inv = 1.0f / (l + 1e-16f);
  float res = a0*inv + bias[lane];
  size_t oi = (size_t)node*64 + lane;
  if (flag[0]) ((float*)out)[oi] = res;
  else         ((unsigned short*)out)[oi] = f2bf(res);
}

// ---------------- host ----------------

extern "C" void kernel_launch(void* const* d_in, const int* in_sizes, int n_in,
                              void* d_out, int out_size, void* d_ws, size_t ws_size,
                              hipStream_t stream)
{
  (void)n_in; (void)out_size; (void)ws_size;
  const void* x   = d_in[0];
  const int*  ei  = (const int*)d_in[1];
  const void* ew  = d_in[2];

  const int N = in_sizes[0] / 128;
  const int E = in_sizes[2];
  const int ET = E + N;
  const int nB = (N + 255) / 256;

  char* p = (char*)d_ws;
  size_t off = 0;
  auto carve = [&](size_t bytes)->void* {
    void* r = p + off;
    off = (off + bytes + 255) & ~(size_t)255;
    return r;
  };
  int*            flag    = (int*)carve(4);
  int*            cnt     = (int*)carve((size_t)N*4);
  float*          wsum    = (float*)carve((size_t)N*4);
  int*            rowptr  = (int*)carve((size_t)(N+1)*4);
  int*            fill    = (int*)carve((size_t)N*4);
  int*            bsum    = (int*)carve((size_t)nB*4);
  int*            boff    = (int*)carve((size_t)nB*4);
  int*            csr_src = (int*)carve((size_t)ET*4);
  float*          csr_w   = (float*)carve((size_t)ET*4);
  float*          ewc     = (float*)carve((size_t)E*4);
  float*          prm     = (float*)carve(17*128*4);
  unsigned short* WT0l    = (unsigned short*)carve(128*128*2);
  unsigned short* WT0r    = (unsigned short*)carve(128*128*2);
  unsigned short* WT1l    = (unsigned short*)carve(128*128*2);
  unsigned short* WT1r    = (unsigned short*)carve(128*128*2);
  unsigned short* WT2l    = (unsigned short*)carve(128*64*2);
  unsigned short* WT2r    = (unsigned short*)carve(128*64*2);
  unsigned short* xc      = (unsigned short*)carve((size_t)N*128*2);
  float*          xlb     = (float*)carve((size_t)N*128*4);
  float*          xrb     = (float*)carve((size_t)N*128*4);
  unsigned short* hb      = (unsigned short*)carve((size_t)N*128*2);

  float* bl0c = prm + 0*128;  float* br0c = prm + 1*128;
  float* We0c = prm + 2*128;  float* at0c = prm + 3*128;  float* bi0c = prm + 4*128;
  float* bl1c = prm + 5*128;  float* br1c = prm + 6*128;
  float* We1c = prm + 7*128;  float* at1c = prm + 8*128;  float* bi1c = prm + 9*128;
  float* bl2c = prm + 10*128; float* br2c = prm + 11*128;
  float* We2c = prm + 12*128; float* at2c = prm + 13*128; float* bi2c = prm + 14*128;

  hipMemsetAsync(cnt,  0, (size_t)N*4, stream);
  hipMemsetAsync(wsum, 0, (size_t)N*4, stream);

  k_detect<<<1, 256, 0, stream>>>((const unsigned short*)x, flag);

  ParamTab pt;
  {
    const void* srcs[17] = { d_in[4], d_in[6], d_in[7], d_in[8], d_in[9],
                             d_in[11], d_in[13], d_in[14], d_in[15], d_in[16],
                             d_in[18], d_in[20], d_in[21], d_in[22], d_in[23],
                             d_in[4], d_in[4] };
    float* dsts[17] = { bl0c, br0c, We0c, at0c, bi0c,
                        bl1c, br1c, We1c, at1c, bi1c,
                        bl2c, br2c, We2c, at2c, bi2c,
                        prm + 15*128, prm + 16*128 };
    int ns[17] = {128,128,128,128,128, 128,128,128,128,128, 64,64,64,64,64, 0,0};
    for (int i = 0; i < 17; i++){ pt.src[i] = srcs[i]; pt.dst[i] = dsts[i]; pt.n[i] = ns[i]; }
  }
  k_canon_params<<<17, 128, 0, stream>>>(pt, flag);
  k_canon_f32<<<(E+255)/256, 256, 0, stream>>>(ew, ewc, E, flag);
  k_canon_bf16<<<((size_t)N*128+255)/256, 256, 0, stream>>>(x, xc, N*128, flag);

  WTab wt;
  {
    const void* srcs[6] = { d_in[3], d_in[5], d_in[10], d_in[12], d_in[17], d_in[19] };
    unsigned short* dsts[6] = { WT0l, WT0r, WT1l, WT1r, WT2l, WT2r };
    int Ms[6] = {128, 128, 128, 128, 64, 64};
    for (int i = 0; i < 6; i++){ wt.src[i] = srcs[i]; wt.dst[i] = dsts[i]; wt.M[i] = Ms[i]; }
  }
  k_canonT<<<dim3(64, 6), 256, 0, stream>>>(wt, flag);

  // graph build
  k_hist <<<(E+255)/256, 256, 0, stream>>>(ei, ewc, cnt, wsum, E, N);
  k_scan1<<<nB, 256, 0, stream>>>(cnt, bsum, N);
  k_scan2<<<1, 1024, 0, stream>>>(bsum, boff, nB);
  k_scan3<<<nB, 256, 0, stream>>>(cnt, boff, rowptr, N);
  k_self <<<(N+255)/256, 256, 0, stream>>>(rowptr, cnt, wsum, fill, csr_src, csr_w, N, ET);
  k_scatter<<<(E+255)/256, 256, 0, stream>>>(ei, ewc, fill, csr_src, csr_w, E, N, ET);

  const int rowBlocks = (N + 63) / 64;

  // layer 0
  k_gemm<<<dim3(rowBlocks, 4), 64, 0, stream>>>(xc, WT0l, WT0r, bl0c, br0c, xlb, xrb, N, 128);
  k_edge128<<<(N+3)/4, 256, 0, stream>>>(xlb, xrb, rowptr, csr_src, csr_w, We0c, at0c, bi0c, hb, N, ET);

  // layer 1
  k_gemm<<<dim3(rowBlocks, 4), 64, 0, stream>>>(hb, WT1l, WT1r, bl1c, br1c, xlb, xrb, N, 128);
  k_edge128<<<(N+3)/4, 256, 0, stream>>>(xlb, xrb, rowptr, csr_src, csr_w, We1c, at1c, bi1c, hb, N, ET);

  // layer 2
  k_gemm<<<dim3(rowBlocks, 2), 64, 0, stream>>>(hb, WT2l, WT2r, bl2c, br2c, xlb, xrb, N, 64);
  k_edge64<<<(N+3)/4, 256, 0, stream>>>(xlb, xrb, rowptr, csr_src, csr_w, We2c, at2c, bi2c,
                                        d_out, N, ET, flag);
}

// Round 6
// 603.022 us; speedup vs baseline: 1.4629x; 1.4629x over previous
//
#include <hip/hip_runtime.h>
#include <cstdint>
#include <cstddef>

typedef __bf16 bf16x8 __attribute__((ext_vector_type(8)));
typedef float f32x4 __attribute__((ext_vector_type(4)));

__device__ __forceinline__ float bf2f(unsigned short u){
  unsigned int x = ((unsigned int)u) << 16;
  return __builtin_bit_cast(float, x);
}
__device__ __forceinline__ unsigned short f2bf(float f){
  unsigned int x = __builtin_bit_cast(unsigned int, f);
  x += 0x7fffu + ((x >> 16) & 1u);
  return (unsigned short)(x >> 16);
}

// ---------------- dtype detect + canonicalize ----------------
__global__ void k_detect(const unsigned short* __restrict__ xs, int* __restrict__ flag){
  __shared__ int found;
  if (threadIdx.x == 0) found = 0;
  __syncthreads();
  for (int i = threadIdx.x; i < 4096; i += 256){
    unsigned short u = xs[i];
    int expo = (u >> 7) & 0xFF;
    if (expo >= 0xC0) atomicOr(&found, 1);
  }
  __syncthreads();
  if (threadIdx.x == 0) flag[0] = found;
}

struct ParamTab {
  const void* src[17];
  float*      dst[17];
  int         n[17];
};
__global__ void k_canon_params(ParamTab t, const int* __restrict__ flag){
  int b = blockIdx.x, i = threadIdx.x;
  if (i < t.n[b]){
    t.dst[b][i] = flag[0] ? ((const float*)t.src[b])[i]
                          : bf2f(((const unsigned short*)t.src[b])[i]);
  }
}

__global__ void k_canon_f32(const void* __restrict__ src, float* __restrict__ dst,
                            int n, const int* __restrict__ flag){
  int i = blockIdx.x*256 + threadIdx.x;
  if (i < n){
    dst[i] = flag[0] ? ((const float*)src)[i]
                     : bf2f(((const unsigned short*)src)[i]);
  }
}

__global__ void k_canon_bf16(const void* __restrict__ src, unsigned short* __restrict__ dst,
                             int n, const int* __restrict__ flag){
  int i = blockIdx.x*256 + threadIdx.x;
  if (i < n){
    dst[i] = flag[0] ? f2bf(((const float*)src)[i])
                     : ((const unsigned short*)src)[i];
  }
}

struct WTab {
  const void* src[6];
  unsigned short* dst[6];
  int M[6];
};
__global__ void k_canonT(WTab t, const int* __restrict__ flag){
  int b = blockIdx.y;
  int M = t.M[b];
  int idx = blockIdx.x*256 + threadIdx.x;
  if (idx < 128*M){
    int k = idx / M, m = idx % M;
    unsigned short v = flag[0] ? f2bf(((const float*)t.src[b])[idx])
                               : ((const unsigned short*)t.src[b])[idx];
    t.dst[b][m*128 + k] = v;
  }
}

// ---------------- graph build ----------------

__global__ void k_hist(const int* __restrict__ ei, const float* __restrict__ ewc,
                       int* __restrict__ cnt, float* __restrict__ wsum, int E, int n){
  int e = blockIdx.x*256 + threadIdx.x;
  if (e < E){
    int d = ei[E + e];
    if ((unsigned)d < (unsigned)n){
      atomicAdd(&cnt[d], 1);
      atomicAdd(&wsum[d], ewc[e]);
    }
  }
}

__global__ void k_scan1(const int* __restrict__ cnt, int* __restrict__ bsum, int n){
  int i = blockIdx.x*256 + threadIdx.x;
  int lane = threadIdx.x & 63, w = threadIdx.x >> 6;
  int v = (i < n) ? cnt[i] + 1 : 0;
  for (int off = 32; off; off >>= 1) v += __shfl_down(v, off);
  __shared__ int ws[4];
  if (lane == 0) ws[w] = v;
  __syncthreads();
  if (threadIdx.x == 0) bsum[blockIdx.x] = ws[0] + ws[1] + ws[2] + ws[3];
}

__global__ void k_scan2(const int* __restrict__ bsum, int* __restrict__ boff, int B){
  int tid = threadIdx.x, lane = tid & 63, w = tid >> 6;
  __shared__ int ws[16];
  int v = (tid < B) ? bsum[tid] : 0;
  int sv = v;
  for (int off = 1; off < 64; off <<= 1){
    int t = __shfl_up(sv, off);
    if (lane >= off) sv += t;
  }
  if (lane == 63) ws[w] = sv;
  __syncthreads();
  if (tid == 0){
    int acc = 0;
    for (int k = 0; k < 16; k++){ int t = ws[k]; ws[k] = acc; acc += t; }
  }
  __syncthreads();
  if (tid < B) boff[tid] = ws[w] + sv - v;
}

__global__ void k_scan3(const int* __restrict__ cnt, const int* __restrict__ boff,
                        int* __restrict__ rowptr, int n){
  int b = blockIdx.x, tid = threadIdx.x;
  int i = b*256 + tid;
  int lane = tid & 63, w = tid >> 6;
  __shared__ int ws[4];
  int v = (i < n) ? cnt[i] + 1 : 0;
  int sv = v;
  for (int off = 1; off < 64; off <<= 1){
    int t = __shfl_up(sv, off);
    if (lane >= off) sv += t;
  }
  if (lane == 63) ws[w] = sv;
  __syncthreads();
  if (tid == 0){
    int acc = 0;
    for (int k = 0; k < 4; k++){ int t = ws[k]; ws[k] = acc; acc += t; }
  }
  __syncthreads();
  if (i < n) rowptr[i + 1] = boff[b] + ws[w] + sv;
  if (i == 0) rowptr[0] = 0;
}

__global__ void k_self(const int* __restrict__ rowptr, const int* __restrict__ cnt,
                       const float* __restrict__ wsum, int* __restrict__ fill,
                       int* __restrict__ csr_src, float* __restrict__ csr_w, int n, int ET){
  int i = blockIdx.x*256 + threadIdx.x;
  if (i < n){
    fill[i] = rowptr[i];
    int slot = rowptr[i+1] - 1;
    if ((unsigned)slot < (unsigned)ET){
      csr_src[slot] = i;
      csr_w[slot] = wsum[i] / fmaxf((float)cnt[i], 1.0f);
    }
  }
}

__global__ void k_scatter(const int* __restrict__ ei, const float* __restrict__ ewc,
                          int* __restrict__ fill, int* __restrict__ csr_src,
                          float* __restrict__ csr_w, int E, int n, int ET){
  int e = blockIdx.x*256 + threadIdx.x;
  if (e < E){
    int s = ei[e], d = ei[E + e];
    if ((unsigned)d < (unsigned)n){
      int pos = atomicAdd(&fill[d], 1);
      if ((unsigned)pos < (unsigned)ET){
        csr_src[pos] = s;
        csr_w[pos] = ewc[e];
      }
    }
  }
}

// ---------------- GEMM: out = A(nrows x 128, bf16) @ W(128 x NC) + b ----------------
// One wave per block computes 64 rows x NC cols (all col-tiles -> A read once
// per output tensor, not once per 64-col slice). OUT_BF16 packs xl for the
// edge-gather (halves gather bytes); f32 for xr.

template<int NC, bool OUT_BF16>
__global__ __launch_bounds__(64) void k_gemmT(
  const unsigned short* __restrict__ A,
  const unsigned short* __restrict__ WT,
  const float* __restrict__ bia,
  void* __restrict__ out,
  int nrows)
{
  constexpr int CT = NC / 16;
  int lane = threadIdx.x;
  int q = lane >> 4, rr = lane & 15;
  int r0 = blockIdx.x * 64;

  f32x4 acc[4][CT];
  for (int a = 0; a < 4; a++)
    for (int b = 0; b < CT; b++)
      acc[a][b] = (f32x4){0.f, 0.f, 0.f, 0.f};

  for (int kc = 0; kc < 4; kc++){
    bf16x8 af[4], bfr[CT];
    #pragma unroll
    for (int rt = 0; rt < 4; rt++){
      int row = r0 + rt*16 + rr;
      if (row >= nrows) row = nrows - 1;
      af[rt] = *(const bf16x8*)(A + (size_t)row*128 + kc*32 + q*8);
    }
    #pragma unroll
    for (int ct = 0; ct < CT; ct++)
      bfr[ct] = *(const bf16x8*)(WT + (size_t)(ct*16 + rr)*128 + kc*32 + q*8);
    #pragma unroll
    for (int rt = 0; rt < 4; rt++)
      #pragma unroll
      for (int ct = 0; ct < CT; ct++)
        acc[rt][ct] = __builtin_amdgcn_mfma_f32_16x16x32_bf16(af[rt], bfr[ct], acc[rt][ct], 0, 0, 0);
  }

  // C/D layout: col = lane&15, row = (lane>>4)*4 + reg
  #pragma unroll
  for (int ct = 0; ct < CT; ct++){
    int col = ct*16 + rr;
    float bv = bia[col];
    #pragma unroll
    for (int rt = 0; rt < 4; rt++){
      #pragma unroll
      for (int t = 0; t < 4; t++){
        int row = r0 + rt*16 + q*4 + t;
        if (row < nrows){
          float v = acc[rt][ct][t] + bv;
          if (OUT_BF16) ((unsigned short*)out)[(size_t)row*NC + col] = f2bf(v);
          else          ((float*)out)[(size_t)row*NC + col] = v;
        }
      }
    }
  }
}

// ---------------- fused edge scoring + online-softmax aggregation ----------------
// Round-4 structure (one coalesced row read per edge, used for both score and
// aggregation) with bf16 xl rows: half the gather bytes.

__global__ __launch_bounds__(256) void k_edge128(
  const unsigned short* __restrict__ xl, const float* __restrict__ xr,
  const int* __restrict__ rowptr, const int* __restrict__ csr_src, const float* __restrict__ csr_w,
  const float* __restrict__ We, const float* __restrict__ att,
  const float* __restrict__ bias, unsigned short* __restrict__ out, int n, int ET)
{
  int wid = threadIdx.x >> 6;
  int lane = threadIdx.x & 63;
  int node = blockIdx.x*4 + wid;
  if (node >= n) return;
  int ch = lane*2;
  float we0 = We[ch],  we1 = We[ch+1];
  float at0 = att[ch], at1 = att[ch+1];
  float2 xrv = *(const float2*)(xr + (size_t)node*128 + ch);
  float fxr0 = xrv.x, fxr1 = xrv.y;
  const unsigned short* xlc = xl + ch;
  int beg = rowptr[node], end = rowptr[node+1];
  if (beg < 0) beg = 0;
  if (end > ET) end = ET;
  float m = -1e30f, l = 0.f, a0 = 0.f, a1 = 0.f;

  for (int base = beg; base < end; base += 64){
    int idx = base + lane;
    int   sv = 0; float wv = 0.f;
    if (idx < end){ sv = csr_src[idx]; wv = csr_w[idx]; }
    if ((unsigned)sv >= (unsigned)n) sv = 0;
    int c = end - base; if (c > 64) c = 64;
    int i = 0;
    for (; i + 4 <= c; i += 4){
      int   s0 = __shfl(sv, i),   s1 = __shfl(sv, i+1),
            s2 = __shfl(sv, i+2), s3 = __shfl(sv, i+3);
      float w0 = __shfl(wv, i),   w1 = __shfl(wv, i+1),
            w2 = __shfl(wv, i+2), w3 = __shfl(wv, i+3);
      unsigned int u0 = *(const unsigned int*)(xlc + (size_t)s0*128);
      unsigned int u1 = *(const unsigned int*)(xlc + (size_t)s1*128);
      unsigned int u2 = *(const unsigned int*)(xlc + (size_t)s2*128);
      unsigned int u3 = *(const unsigned int*)(xlc + (size_t)s3*128);
      float v0x = bf2f((unsigned short)(u0 & 0xffffu)), v0y = bf2f((unsigned short)(u0 >> 16));
      float v1x = bf2f((unsigned short)(u1 & 0xffffu)), v1y = bf2f((unsigned short)(u1 >> 16));
      float v2x = bf2f((unsigned short)(u2 & 0xffffu)), v2y = bf2f((unsigned short)(u2 >> 16));
      float v3x = bf2f((unsigned short)(u3 & 0xffffu)), v3y = bf2f((unsigned short)(u3 >> 16));
      float p0, p1, p2, p3;
      {
        float t0 = v0x + fxr0 + w0*we0, t1 = v0y + fxr1 + w0*we1;
        t0 = t0 > 0.f ? t0 : 0.2f*t0;  t1 = t1 > 0.f ? t1 : 0.2f*t1;
        p0 = t0*at0 + t1*at1;
      }{
        float t0 = v1x + fxr0 + w1*we0, t1 = v1y + fxr1 + w1*we1;
        t0 = t0 > 0.f ? t0 : 0.2f*t0;  t1 = t1 > 0.f ? t1 : 0.2f*t1;
        p1 = t0*at0 + t1*at1;
      }{
        float t0 = v2x + fxr0 + w2*we0, t1 = v2y + fxr1 + w2*we1;
        t0 = t0 > 0.f ? t0 : 0.2f*t0;  t1 = t1 > 0.f ? t1 : 0.2f*t1;
        p2 = t0*at0 + t1*at1;
      }{
        float t0 = v3x + fxr0 + w3*we0, t1 = v3y + fxr1 + w3*we1;
        t0 = t0 > 0.f ? t0 : 0.2f*t0;  t1 = t1 > 0.f ? t1 : 0.2f*t1;
        p3 = t0*at0 + t1*at1;
      }
      for (int d = 1; d <= 8; d <<= 1){
        p0 += __shfl_xor(p0, d, 16);
        p1 += __shfl_xor(p1, d, 16);
        p2 += __shfl_xor(p2, d, 16);
        p3 += __shfl_xor(p3, d, 16);
      }
      float mx = fmaxf(fmaxf(p0, p1), fmaxf(p2, p3));
      float nm = fmaxf(m, mx);
      float sc = __expf(m - nm);
      float e0 = __expf(p0 - nm), e1 = __expf(p1 - nm);
      float e2 = __expf(p2 - nm), e3 = __expf(p3 - nm);
      l  = l*sc  + ((e0 + e1) + (e2 + e3));
      a0 = a0*sc + ((e0*v0x + e1*v1x) + (e2*v2x + e3*v3x));
      a1 = a1*sc + ((e0*v0y + e1*v1y) + (e2*v2y + e3*v3y));
      m = nm;
    }
    for (; i < c; i++){
      int   s = __shfl(sv, i);
      float w = __shfl(wv, i);
      unsigned int u = *(const unsigned int*)(xlc + (size_t)s*128);
      float x0 = bf2f((unsigned short)(u & 0xffffu));
      float x1 = bf2f((unsigned short)(u >> 16));
      float t0 = x0 + fxr0 + w*we0;
      float t1 = x1 + fxr1 + w*we1;
      t0 = t0 > 0.f ? t0 : 0.2f*t0;
      t1 = t1 > 0.f ? t1 : 0.2f*t1;
      float p = t0*at0 + t1*at1;
      p += __shfl_xor(p, 1, 16);
      p += __shfl_xor(p, 2, 16);
      p += __shfl_xor(p, 4, 16);
      p += __shfl_xor(p, 8, 16);
      float nm = fmaxf(m, p);
      float sc = __expf(m - nm);
      float pe = __expf(p - nm);
      l  = l*sc  + pe;
      a0 = a0*sc + pe*x0;
      a1 = a1*sc + pe*x1;
      m = nm;
    }
  }
  float inv = 1.0f / (l + 1e-16f);
  float o0 = a0*inv + bias[ch];
  float o1 = a1*inv + bias[ch+1];
  o0 = o0 > 0.f ? o0 : (__expf(o0) - 1.0f);   // ELU (layers 0,1)
  o1 = o1 > 0.f ? o1 : (__expf(o1) - 1.0f);
  unsigned int packed = (unsigned int)f2bf(o0) | ((unsigned int)f2bf(o1) << 16);
  *(unsigned int*)(out + (size_t)node*128 + ch) = packed;
}

// OUT=64, 1 head: lane == channel. bf16 xl rows (128B/edge).
__global__ __launch_bounds__(256) void k_edge64(
  const unsigned short* __restrict__ xl, const float* __restrict__ xr,
  const int* __restrict__ rowptr, const int* __restrict__ csr_src, const float* __restrict__ csr_w,
  const float* __restrict__ We, const float* __restrict__ att,
  const float* __restrict__ bias, void* __restrict__ out, int n, int ET,
  const int* __restrict__ flag)
{
  int wid = threadIdx.x >> 6;
  int lane = threadIdx.x & 63;
  int node = blockIdx.x*4 + wid;
  if (node >= n) return;
  float we0 = We[lane];
  float at0 = att[lane];
  float fxr0 = xr[(size_t)node*64 + lane];
  const unsigned short* xlc = xl + lane;
  int beg = rowptr[node], end = rowptr[node+1];
  if (beg < 0) beg = 0;
  if (end > ET) end = ET;
  float m = -1e30f, l = 0.f, a0 = 0.f;

  for (int base = beg; base < end; base += 64){
    int idx = base + lane;
    int   sv = 0; float wv = 0.f;
    if (idx < end){ sv = csr_src[idx]; wv = csr_w[idx]; }
    if ((unsigned)sv >= (unsigned)n) sv = 0;
    int c = end - base; if (c > 64) c = 64;
    int i = 0;
    for (; i + 4 <= c; i += 4){
      int   s0 = __shfl(sv, i),   s1 = __shfl(sv, i+1),
            s2 = __shfl(sv, i+2), s3 = __shfl(sv, i+3);
      float w0 = __shfl(wv, i),   w1 = __shfl(wv, i+1),
            w2 = __shfl(wv, i+2), w3 = __shfl(wv, i+3);
      float x0 = bf2f(xlc[(size_t)s0*64]);
      float x1 = bf2f(xlc[(size_t)s1*64]);
      float x2 = bf2f(xlc[(size_t)s2*64]);
      float x3 = bf2f(xlc[(size_t)s3*64]);
      float t0 = x0 + fxr0 + w0*we0;  t0 = t0 > 0.f ? t0 : 0.2f*t0;
      float t1 = x1 + fxr0 + w1*we0;  t1 = t1 > 0.f ? t1 : 0.2f*t1;
      float t2 = x2 + fxr0 + w2*we0;  t2 = t2 > 0.f ? t2 : 0.2f*t2;
      float t3 = x3 + fxr0 + w3*we0;  t3 = t3 > 0.f ? t3 : 0.2f*t3;
      float p0 = t0*at0, p1 = t1*at0, p2 = t2*at0, p3 = t3*at0;
      for (int d = 1; d < 64; d <<= 1){
        p0 += __shfl_xor(p0, d);
        p1 += __shfl_xor(p1, d);
        p2 += __shfl_xor(p2, d);
        p3 += __shfl_xor(p3, d);
      }
      float mx = fmaxf(fmaxf(p0, p1), fmaxf(p2, p3));
      float nm = fmaxf(m, mx);
      float sc = __expf(m - nm);
      float e0 = __expf(p0 - nm), e1 = __expf(p1 - nm);
      float e2 = __expf(p2 - nm), e3 = __expf(p3 - nm);
      l  = l*sc  + ((e0 + e1) + (e2 + e3));
      a0 = a0*sc + ((e0*x0 + e1*x1) + (e2*x2 + e3*x3));
      m = nm;
    }
    for (; i < c; i++){
      int   s = __shfl(sv, i);
      float w = __shfl(wv, i);
      float x0 = bf2f(xlc[(size_t)s*64]);
      float t0 = x0 + fxr0 + w*we0;
      t0 = t0 > 0.f ? t0 : 0.2f*t0;
      float p = t0*at0;
      for (int d = 1; d < 64; d <<= 1) p += __shfl_xor(p, d);
      float nm = fmaxf(m, p);
      float sc = __expf(m - nm);
      float pe = __expf(p - nm);
      l  = l*sc  + pe;
      a0 = a0*sc + pe*x0;
      m = nm;
    }
  }
  float inv = 1.0f / (l + 1e-16f);
  float res = a0*inv + bias[lane];
  size_t oi = (size_t)node*64 + lane;
  if (flag[0]) ((float*)out)[oi] = res;
  else         ((unsigned short*)out)[oi] = f2bf(res);
}

// ---------------- host ----------------

extern "C" void kernel_launch(void* const* d_in, const int* in_sizes, int n_in,
                              void* d_out, int out_size, void* d_ws, size_t ws_size,
                              hipStream_t stream)
{
  (void)n_in; (void)out_size; (void)ws_size;
  const void* x   = d_in[0];
  const int*  ei  = (const int*)d_in[1];
  const void* ew  = d_in[2];

  const int N = in_sizes[0] / 128;
  const int E = in_sizes[2];
  const int ET = E + N;
  const int nB = (N + 255) / 256;

  char* p = (char*)d_ws;
  size_t off = 0;
  auto carve = [&](size_t bytes)->void* {
    void* r = p + off;
    off = (off + bytes + 255) & ~(size_t)255;
    return r;
  };
  int*            flag    = (int*)carve(4);
  int*            cnt     = (int*)carve((size_t)N*4);
  float*          wsum    = (float*)carve((size_t)N*4);
  int*            rowptr  = (int*)carve((size_t)(N+1)*4);
  int*            fill    = (int*)carve((size_t)N*4);
  int*            bsum    = (int*)carve((size_t)nB*4);
  int*            boff    = (int*)carve((size_t)nB*4);
  int*            csr_src = (int*)carve((size_t)ET*4);
  float*          csr_w   = (float*)carve((size_t)ET*4);
  float*          ewc     = (float*)carve((size_t)E*4);
  float*          prm     = (float*)carve(17*128*4);
  unsigned short* WT0l    = (unsigned short*)carve(128*128*2);
  unsigned short* WT0r    = (unsigned short*)carve(128*128*2);
  unsigned short* WT1l    = (unsigned short*)carve(128*128*2);
  unsigned short* WT1r    = (unsigned short*)carve(128*128*2);
  unsigned short* WT2l    = (unsigned short*)carve(128*64*2);
  unsigned short* WT2r    = (unsigned short*)carve(128*64*2);
  unsigned short* xc      = (unsigned short*)carve((size_t)N*128*2);
  unsigned short* xlb16   = (unsigned short*)carve((size_t)N*128*2);   // bf16 xl (gathered)
  float*          xrb     = (float*)carve((size_t)N*128*4);            // f32 xr (sequential)
  unsigned short* hb      = (unsigned short*)carve((size_t)N*128*2);

  float* bl0c = prm + 0*128;  float* br0c = prm + 1*128;
  float* We0c = prm + 2*128;  float* at0c = prm + 3*128;  float* bi0c = prm + 4*128;
  float* bl1c = prm + 5*128;  float* br1c = prm + 6*128;
  float* We1c = prm + 7*128;  float* at1c = prm + 8*128;  float* bi1c = prm + 9*128;
  float* bl2c = prm + 10*128; float* br2c = prm + 11*128;
  float* We2c = prm + 12*128; float* at2c = prm + 13*128; float* bi2c = prm + 14*128;

  hipMemsetAsync(cnt,  0, (size_t)N*4, stream);
  hipMemsetAsync(wsum, 0, (size_t)N*4, stream);

  k_detect<<<1, 256, 0, stream>>>((const unsigned short*)x, flag);

  ParamTab pt;
  {
    const void* srcs[17] = { d_in[4], d_in[6], d_in[7], d_in[8], d_in[9],
                             d_in[11], d_in[13], d_in[14], d_in[15], d_in[16],
                             d_in[18], d_in[20], d_in[21], d_in[22], d_in[23],
                             d_in[4], d_in[4] };
    float* dsts[17] = { bl0c, br0c, We0c, at0c, bi0c,
                        bl1c, br1c, We1c, at1c, bi1c,
                        bl2c, br2c, We2c, at2c, bi2c,
                        prm + 15*128, prm + 16*128 };
    int ns[17] = {128,128,128,128,128, 128,128,128,128,128, 64,64,64,64,64, 0,0};
    for (int i = 0; i < 17; i++){ pt.src[i] = srcs[i]; pt.dst[i] = dsts[i]; pt.n[i] = ns[i]; }
  }
  k_canon_params<<<17, 128, 0, stream>>>(pt, flag);
  k_canon_f32<<<(E+255)/256, 256, 0, stream>>>(ew, ewc, E, flag);
  k_canon_bf16<<<((size_t)N*128+255)/256, 256, 0, stream>>>(x, xc, N*128, flag);

  WTab wt;
  {
    const void* srcs[6] = { d_in[3], d_in[5], d_in[10], d_in[12], d_in[17], d_in[19] };
    unsigned short* dsts[6] = { WT0l, WT0r, WT1l, WT1r, WT2l, WT2r };
    int Ms[6] = {128, 128, 128, 128, 64, 64};
    for (int i = 0; i < 6; i++){ wt.src[i] = srcs[i]; wt.dst[i] = dsts[i]; wt.M[i] = Ms[i]; }
  }
  k_canonT<<<dim3(64, 6), 256, 0, stream>>>(wt, flag);

  // graph build
  k_hist <<<(E+255)/256, 256, 0, stream>>>(ei, ewc, cnt, wsum, E, N);
  k_scan1<<<nB, 256, 0, stream>>>(cnt, bsum, N);
  k_scan2<<<1, 1024, 0, stream>>>(bsum, boff, nB);
  k_scan3<<<nB, 256, 0, stream>>>(cnt, boff, rowptr, N);
  k_self <<<(N+255)/256, 256, 0, stream>>>(rowptr, cnt, wsum, fill, csr_src, csr_w, N, ET);
  k_scatter<<<(E+255)/256, 256, 0, stream>>>(ei, ewc, fill, csr_src, csr_w, E, N, ET);

  const int rowBlocks = (N + 63) / 64;

  // layer 0
  k_gemmT<128,true ><<<rowBlocks, 64, 0, stream>>>(xc, WT0l, bl0c, xlb16, N);
  k_gemmT<128,false><<<rowBlocks, 64, 0, stream>>>(xc, WT0r, br0c, xrb,   N);
  k_edge128<<<(N+3)/4, 256, 0, stream>>>(xlb16, xrb, rowptr, csr_src, csr_w, We0c, at0c, bi0c, hb, N, ET);

  // layer 1
  k_gemmT<128,true ><<<rowBlocks, 64, 0, stream>>>(hb, WT1l, bl1c, xlb16, N);
  k_gemmT<128,false><<<rowBlocks, 64, 0, stream>>>(hb, WT1r, br1c, xrb,   N);
  k_edge128<<<(N+3)/4, 256, 0, stream>>>(xlb16, xrb, rowptr, csr_src, csr_w, We1c, at1c, bi1c, hb, N, ET);

  // layer 2
  k_gemmT<64,true ><<<rowBlocks, 64, 0, stream>>>(hb, WT2l, bl2c, xlb16, N);
  k_gemmT<64,false><<<rowBlocks, 64, 0, stream>>>(hb, WT2r, br2c, xrb,   N);
  k_edge64<<<(N+3)/4, 256, 0, stream>>>(xlb16, xrb, rowptr, csr_src, csr_w, We2c, at2c, bi2c,
                                        d_out, N, ET, flag);
}

// Round 7
// 539.232 us; speedup vs baseline: 1.6360x; 1.1183x over previous
//
#include <hip/hip_runtime.h>
#include <cstdint>
#include <cstddef>

typedef __bf16 bf16x8 __attribute__((ext_vector_type(8)));
typedef float f32x4 __attribute__((ext_vector_type(4)));

__device__ __forceinline__ float bf2f(unsigned short u){
  unsigned int x = ((unsigned int)u) << 16;
  return __builtin_bit_cast(float, x);
}
__device__ __forceinline__ unsigned short f2bf(float f){
  unsigned int x = __builtin_bit_cast(unsigned int, f);
  x += 0x7fffu + ((x >> 16) & 1u);
  return (unsigned short)(x >> 16);
}

// ---- DS-free cross-lane helpers: readlane (VALU) + DPP reductions ----
__device__ __forceinline__ int rl_i(int v, int l){ return __builtin_amdgcn_readlane(v, l); }
__device__ __forceinline__ float rl_f(float v, int l){
  return __builtin_bit_cast(float, __builtin_amdgcn_readlane(__builtin_bit_cast(int, v), l));
}
template<int C> __device__ __forceinline__ float dpp_add(float x){
  int y = __builtin_amdgcn_update_dpp(0, __builtin_bit_cast(int, x), C, 0xF, 0xF, true);
  return x + __builtin_bit_cast(float, y);
}
// sum across each 16-lane row (all lanes of the row get the row sum)
__device__ __forceinline__ float sum16(float x){
  x = dpp_add<0xB1>(x);    // quad_perm [1,0,3,2]
  x = dpp_add<0x4E>(x);    // quad_perm [2,3,0,1]
  x = dpp_add<0x124>(x);   // row_ror:4
  x = dpp_add<0x128>(x);   // row_ror:8
  return x;
}
// full 64-lane sum, result uniform
__device__ __forceinline__ float sum64(float x){
  x = sum16(x);
  return (rl_f(x, 0) + rl_f(x, 16)) + (rl_f(x, 32) + rl_f(x, 48));
}

__device__ __forceinline__ float load_w(const void* ew, int e, int f){
  return f ? ((const float*)ew)[e] : bf2f(((const unsigned short*)ew)[e]);
}

// ---------------- dtype detect + canonicalize ----------------
__global__ void k_detect(const unsigned short* __restrict__ xs, int* __restrict__ flag){
  __shared__ int found;
  if (threadIdx.x == 0) found = 0;
  __syncthreads();
  for (int i = threadIdx.x; i < 4096; i += 256){
    unsigned short u = xs[i];
    int expo = (u >> 7) & 0xFF;
    if (expo >= 0xC0) atomicOr(&found, 1);
  }
  __syncthreads();
  if (threadIdx.x == 0) flag[0] = found;
}

struct ParamTab {
  const void* src[15];
  float*      dst[15];
  int         n[15];
};
__global__ void k_canon_params(ParamTab t, const int* __restrict__ flag){
  int b = blockIdx.x, i = threadIdx.x;
  if (i < t.n[b]){
    t.dst[b][i] = flag[0] ? ((const float*)t.src[b])[i]
                          : bf2f(((const unsigned short*)t.src[b])[i]);
  }
}

// x -> bf16, 4 elements per thread
__global__ void k_canon_bf16v(const void* __restrict__ src, unsigned short* __restrict__ dst,
                              int n4, const int* __restrict__ flag){
  int i = blockIdx.x*256 + threadIdx.x;
  if (i < n4){
    if (flag[0]){
      float4 v = ((const float4*)src)[i];
      ushort4 o;
      o.x = f2bf(v.x); o.y = f2bf(v.y); o.z = f2bf(v.z); o.w = f2bf(v.w);
      ((ushort4*)dst)[i] = o;
    } else {
      ((ushort4*)dst)[i] = ((const ushort4*)src)[i];
    }
  }
}

struct WTab {
  const void* src[6];
  unsigned short* dst[6];
  int M[6];
};
__global__ void k_canonT(WTab t, const int* __restrict__ flag){
  int b = blockIdx.y;
  int M = t.M[b];
  int idx = blockIdx.x*256 + threadIdx.x;
  if (idx < 128*M){
    int k = idx / M, m = idx % M;
    unsigned short v = flag[0] ? f2bf(((const float*)t.src[b])[idx])
                               : ((const unsigned short*)t.src[b])[idx];
    t.dst[b][m*128 + k] = v;
  }
}

// ---------------- graph build ----------------

__global__ void k_hist(const int* __restrict__ ei, const void* __restrict__ ew,
                       int* __restrict__ cnt, float* __restrict__ wsum, int E, int n,
                       const int* __restrict__ flag){
  int e = blockIdx.x*256 + threadIdx.x;
  if (e < E){
    int d = ei[E + e];
    if ((unsigned)d < (unsigned)n){
      atomicAdd(&cnt[d], 1);
      atomicAdd(&wsum[d], load_w(ew, e, flag[0]));
    }
  }
}

__global__ void k_scan1(const int* __restrict__ cnt, int* __restrict__ bsum, int n){
  int i = blockIdx.x*256 + threadIdx.x;
  int lane = threadIdx.x & 63, w = threadIdx.x >> 6;
  int v = (i < n) ? cnt[i] + 1 : 0;
  for (int off = 32; off; off >>= 1) v += __shfl_down(v, off);
  __shared__ int ws[4];
  if (lane == 0) ws[w] = v;
  __syncthreads();
  if (threadIdx.x == 0) bsum[blockIdx.x] = ws[0] + ws[1] + ws[2] + ws[3];
}

__global__ void k_scan2(const int* __restrict__ bsum, int* __restrict__ boff, int B){
  int tid = threadIdx.x, lane = tid & 63, w = tid >> 6;
  __shared__ int ws[16];
  int v = (tid < B) ? bsum[tid] : 0;
  int sv = v;
  for (int off = 1; off < 64; off <<= 1){
    int t = __shfl_up(sv, off);
    if (lane >= off) sv += t;
  }
  if (lane == 63) ws[w] = sv;
  __syncthreads();
  if (tid == 0){
    int acc = 0;
    for (int k = 0; k < 16; k++){ int t = ws[k]; ws[k] = acc; acc += t; }
  }
  __syncthreads();
  if (tid < B) boff[tid] = ws[w] + sv - v;
}

// scan3 + self-loop placement fused
__global__ void k_scan3self(const int* __restrict__ cnt, const int* __restrict__ boff,
                            const float* __restrict__ wsum,
                            int* __restrict__ rowptr, int* __restrict__ fill,
                            int* __restrict__ csr_src, float* __restrict__ csr_w, int n){
  int b = blockIdx.x, tid = threadIdx.x;
  int i = b*256 + tid;
  int lane = tid & 63, w = tid >> 6;
  __shared__ int ws[4];
  int deg = (i < n) ? cnt[i] : 0;
  int v = (i < n) ? deg + 1 : 0;
  int sv = v;
  for (int off = 1; off < 64; off <<= 1){
    int t = __shfl_up(sv, off);
    if (lane >= off) sv += t;
  }
  if (lane == 63) ws[w] = sv;
  __syncthreads();
  if (tid == 0){
    int acc = 0;
    for (int k = 0; k < 4; k++){ int t = ws[k]; ws[k] = acc; acc += t; }
  }
  __syncthreads();
  if (i < n){
    int vend = boff[b] + ws[w] + sv;      // rowptr[i+1]
    rowptr[i + 1] = vend;
    fill[i] = vend - v;                   // rowptr[i]
    csr_src[vend - 1] = i;                // self-loop in last slot
    csr_w[vend - 1] = wsum[i] / fmaxf((float)deg, 1.0f);
  }
  if (i == 0) rowptr[0] = 0;
}

__global__ void k_scatter(const int* __restrict__ ei, const void* __restrict__ ew,
                          int* __restrict__ fill, int* __restrict__ csr_src,
                          float* __restrict__ csr_w, int E, int n, int ET,
                          const int* __restrict__ flag){
  int e = blockIdx.x*256 + threadIdx.x;
  if (e < E){
    int s = ei[e], d = ei[E + e];
    if ((unsigned)d < (unsigned)n){
      int pos = atomicAdd(&fill[d], 1);
      if ((unsigned)pos < (unsigned)ET){
        csr_src[pos] = s;
        csr_w[pos] = load_w(ew, e, flag[0]);
      }
    }
  }
}

// ---------------- GEMM: xl (bf16 out) and xr (f32 out) in one launch ----------------
// blockIdx.y: 0 = L (bf16 out), 1 = R (f32 out). One wave = 64 rows x NC cols.

template<int NC>
__global__ __launch_bounds__(64) void k_gemm2(
  const unsigned short* __restrict__ A,
  const unsigned short* __restrict__ WTl, const unsigned short* __restrict__ WTr,
  const float* __restrict__ bl, const float* __restrict__ br,
  unsigned short* __restrict__ outL, float* __restrict__ outR,
  int nrows)
{
  constexpr int CT = NC / 16;
  int lane = threadIdx.x;
  int q = lane >> 4, rr = lane & 15;
  int r0 = blockIdx.x * 64;
  bool isR = blockIdx.y == 1;
  const unsigned short* WT = isR ? WTr : WTl;
  const float* bia         = isR ? br  : bl;

  f32x4 acc[4][CT];
  for (int a = 0; a < 4; a++)
    for (int b = 0; b < CT; b++)
      acc[a][b] = (f32x4){0.f, 0.f, 0.f, 0.f};

  for (int kc = 0; kc < 4; kc++){
    bf16x8 af[4], bfr[CT];
    #pragma unroll
    for (int rt = 0; rt < 4; rt++){
      int row = r0 + rt*16 + rr;
      if (row >= nrows) row = nrows - 1;
      af[rt] = *(const bf16x8*)(A + (size_t)row*128 + kc*32 + q*8);
    }
    #pragma unroll
    for (int ct = 0; ct < CT; ct++)
      bfr[ct] = *(const bf16x8*)(WT + (size_t)(ct*16 + rr)*128 + kc*32 + q*8);
    #pragma unroll
    for (int rt = 0; rt < 4; rt++)
      #pragma unroll
      for (int ct = 0; ct < CT; ct++)
        acc[rt][ct] = __builtin_amdgcn_mfma_f32_16x16x32_bf16(af[rt], bfr[ct], acc[rt][ct], 0, 0, 0);
  }

  // C/D layout: col = lane&15, row = (lane>>4)*4 + reg
  #pragma unroll
  for (int ct = 0; ct < CT; ct++){
    int col = ct*16 + rr;
    float bv = bia[col];
    #pragma unroll
    for (int rt = 0; rt < 4; rt++){
      #pragma unroll
      for (int t = 0; t < 4; t++){
        int row = r0 + rt*16 + q*4 + t;
        if (row < nrows){
          float v = acc[rt][ct][t] + bv;
          if (isR) outR[(size_t)row*NC + col] = v;
          else     outL[(size_t)row*NC + col] = f2bf(v);
        }
      }
    }
  }
}

// ---------------- fused edge scoring + online-softmax aggregation ----------------
// DS-free inner loop: readlane broadcasts + DPP reductions. One coalesced
// bf16 row gather per edge serves both score and aggregation.

__global__ __launch_bounds__(256) void k_edge128(
  const unsigned short* __restrict__ xl, const float* __restrict__ xr,
  const int* __restrict__ rowptr, const int* __restrict__ csr_src, const float* __restrict__ csr_w,
  const float* __restrict__ We, const float* __restrict__ att,
  const float* __restrict__ bias, unsigned short* __restrict__ out, int n, int ET)
{
  int wid = threadIdx.x >> 6;
  int lane = threadIdx.x & 63;
  int node = blockIdx.x*4 + wid;
  if (node >= n) return;
  int ch = lane*2;
  float we0 = We[ch],  we1 = We[ch+1];
  float at0 = att[ch], at1 = att[ch+1];
  float2 xrv = *(const float2*)(xr + (size_t)node*128 + ch);
  float fxr0 = xrv.x, fxr1 = xrv.y;
  const unsigned short* xlc = xl + ch;
  int beg = rowptr[node], end = rowptr[node+1];
  if (beg < 0) beg = 0;
  if (end > ET) end = ET;
  float m = -1e30f, l = 0.f, a0 = 0.f, a1 = 0.f;

  for (int base = beg; base < end; base += 64){
    int idx = base + lane;
    int   sv = 0; float wv = 0.f;
    if (idx < end){ sv = csr_src[idx]; wv = csr_w[idx]; }
    if ((unsigned)sv >= (unsigned)n) sv = 0;
    int c = end - base; if (c > 64) c = 64;
    int i = 0;
    for (; i + 4 <= c; i += 4){
      int   s0 = rl_i(sv, i),   s1 = rl_i(sv, i+1),
            s2 = rl_i(sv, i+2), s3 = rl_i(sv, i+3);
      float w0 = rl_f(wv, i),   w1 = rl_f(wv, i+1),
            w2 = rl_f(wv, i+2), w3 = rl_f(wv, i+3);
      unsigned int u0 = *(const unsigned int*)(xlc + (size_t)s0*128);
      unsigned int u1 = *(const unsigned int*)(xlc + (size_t)s1*128);
      unsigned int u2 = *(const unsigned int*)(xlc + (size_t)s2*128);
      unsigned int u3 = *(const unsigned int*)(xlc + (size_t)s3*128);
      float v0x = bf2f((unsigned short)(u0 & 0xffffu)), v0y = bf2f((unsigned short)(u0 >> 16));
      float v1x = bf2f((unsigned short)(u1 & 0xffffu)), v1y = bf2f((unsigned short)(u1 >> 16));
      float v2x = bf2f((unsigned short)(u2 & 0xffffu)), v2y = bf2f((unsigned short)(u2 >> 16));
      float v3x = bf2f((unsigned short)(u3 & 0xffffu)), v3y = bf2f((unsigned short)(u3 >> 16));
      float p0, p1, p2, p3;
      {
        float t0 = v0x + fxr0 + w0*we0, t1 = v0y + fxr1 + w0*we1;
        t0 = t0 > 0.f ? t0 : 0.2f*t0;  t1 = t1 > 0.f ? t1 : 0.2f*t1;
        p0 = t0*at0 + t1*at1;
      }{
        float t0 = v1x + fxr0 + w1*we0, t1 = v1y + fxr1 + w1*we1;
        t0 = t0 > 0.f ? t0 : 0.2f*t0;  t1 = t1 > 0.f ? t1 : 0.2f*t1;
        p1 = t0*at0 + t1*at1;
      }{
        float t0 = v2x + fxr0 + w2*we0, t1 = v2y + fxr1 + w2*we1;
        t0 = t0 > 0.f ? t0 : 0.2f*t0;  t1 = t1 > 0.f ? t1 : 0.2f*t1;
        p2 = t0*at0 + t1*at1;
      }{
        float t0 = v3x + fxr0 + w3*we0, t1 = v3y + fxr1 + w3*we1;
        t0 = t0 > 0.f ? t0 : 0.2f*t0;  t1 = t1 > 0.f ? t1 : 0.2f*t1;
        p3 = t0*at0 + t1*at1;
      }
      // per-head dot: sum across each 16-lane row (DPP, no DS)
      p0 = sum16(p0); p1 = sum16(p1); p2 = sum16(p2); p3 = sum16(p3);
      float mx = fmaxf(fmaxf(p0, p1), fmaxf(p2, p3));
      float nm = fmaxf(m, mx);
      float sc = __expf(m - nm);
      float e0 = __expf(p0 - nm), e1 = __expf(p1 - nm);
      float e2 = __expf(p2 - nm), e3 = __expf(p3 - nm);
      l  = l*sc  + ((e0 + e1) + (e2 + e3));
      a0 = a0*sc + ((e0*v0x + e1*v1x) + (e2*v2x + e3*v3x));
      a1 = a1*sc + ((e0*v0y + e1*v1y) + (e2*v2y + e3*v3y));
      m = nm;
    }
    for (; i < c; i++){
      int   s = rl_i(sv, i);
      float w = rl_f(wv, i);
      unsigned int u = *(const unsigned int*)(xlc + (size_t)s*128);
      float x0 = bf2f((unsigned short)(u & 0xffffu));
      float x1 = bf2f((unsigned short)(u >> 16));
      float t0 = x0 + fxr0 + w*we0;
      float t1 = x1 + fxr1 + w*we1;
      t0 = t0 > 0.f ? t0 : 0.2f*t0;
      t1 = t1 > 0.f ? t1 : 0.2f*t1;
      float p = sum16(t0*at0 + t1*at1);
      float nm = fmaxf(m, p);
      float sc = __expf(m - nm);
      float pe = __expf(p - nm);
      l  = l*sc  + pe;
      a0 = a0*sc + pe*x0;
      a1 = a1*sc + pe*x1;
      m = nm;
    }
  }
  float inv = 1.0f / (l + 1e-16f);
  float o0 = a0*inv + bias[ch];
  float o1 = a1*inv + bias[ch+1];
  o0 = o0 > 0.f ? o0 : (__expf(o0) - 1.0f);   // ELU (layers 0,1)
  o1 = o1 > 0.f ? o1 : (__expf(o1) - 1.0f);
  unsigned int packed = (unsigned int)f2bf(o0) | ((unsigned int)f2bf(o1) << 16);
  *(unsigned int*)(out + (size_t)node*128 + ch) = packed;
}

// OUT=64, 1 head: lane == channel; 64-lane DPP+readlane reduction.
__global__ __launch_bounds__(256) void k_edge64(
  const unsigned short* __restrict__ xl, const float* __restrict__ xr,
  const int* __restrict__ rowptr, const int* __restrict__ csr_src, const float* __restrict__ csr_w,
  const float* __restrict__ We, const float* __restrict__ att,
  const float* __restrict__ bias, void* __restrict__ out, int n, int ET,
  const int* __restrict__ flag)
{
  int wid = threadIdx.x >> 6;
  int lane = threadIdx.x & 63;
  int node = blockIdx.x*4 + wid;
  if (node >= n) return;
  float we0 = We[lane];
  float at0 = att[lane];
  float fxr0 = xr[(size_t)node*64 + lane];
  const unsigned short* xlc = xl + lane;
  int beg = rowptr[node], end = rowptr[node+1];
  if (beg < 0) beg = 0;
  if (end > ET) end = ET;
  float m = -1e30f, l = 0.f, a0 = 0.f;

  for (int base = beg; base < end; base += 64){
    int idx = base + lane;
    int   sv = 0; float wv = 0.f;
    if (idx < end){ sv = csr_src[idx]; wv = csr_w[idx]; }
    if ((unsigned)sv >= (unsigned)n) sv = 0;
    int c = end - base; if (c > 64) c = 64;
    int i = 0;
    for (; i + 4 <= c; i += 4){
      int   s0 = rl_i(sv, i),   s1 = rl_i(sv, i+1),
            s2 = rl_i(sv, i+2), s3 = rl_i(sv, i+3);
      float w0 = rl_f(wv, i),   w1 = rl_f(wv, i+1),
            w2 = rl_f(wv, i+2), w3 = rl_f(wv, i+3);
      float x0 = bf2f(xlc[(size_t)s0*64]);
      float x1 = bf2f(xlc[(size_t)s1*64]);
      float x2 = bf2f(xlc[(size_t)s2*64]);
      float x3 = bf2f(xlc[(size_t)s3*64]);
      float t0 = x0 + fxr0 + w0*we0;  t0 = t0 > 0.f ? t0 : 0.2f*t0;
      float t1 = x1 + fxr0 + w1*we0;  t1 = t1 > 0.f ? t1 : 0.2f*t1;
      float t2 = x2 + fxr0 + w2*we0;  t2 = t2 > 0.f ? t2 : 0.2f*t2;
      float t3 = x3 + fxr0 + w3*we0;  t3 = t3 > 0.f ? t3 : 0.2f*t3;
      float p0 = sum64(t0*at0);
      float p1 = sum64(t1*at0);
      float p2 = sum64(t2*at0);
      float p3 = sum64(t3*at0);
      float mx = fmaxf(fmaxf(p0, p1), fmaxf(p2, p3));
      float nm = fmaxf(m, mx);
      float sc = __expf(m - nm);
      float e0 = __expf(p0 - nm), e1 = __expf(p1 - nm);
      float e2 = __expf(p2 - nm), e3 = __expf(p3 - nm);
      l  = l*sc  + ((e0 + e1) + (e2 + e3));
      a0 = a0*sc + ((e0*x0 + e1*x1) + (e2*x2 + e3*x3));
      m = nm;
    }
    for (; i < c; i++){
      int   s = rl_i(sv, i);
      float w = rl_f(wv, i);
      float x0 = bf2f(xlc[(size_t)s*64]);
      float t0 = x0 + fxr0 + w*we0;
      t0 = t0 > 0.f ? t0 : 0.2f*t0;
      float p = sum64(t0*at0);
      float nm = fmaxf(m, p);
      float sc = __expf(m - nm);
      float pe = __expf(p - nm);
      l  = l*sc  + pe;
      a0 = a0*sc + pe*x0;
      m = nm;
    }
  }
  float inv = 1.0f / (l + 1e-16f);
  float res = a0*inv + bias[lane];
  size_t oi = (size_t)node*64 + lane;
  if (flag[0]) ((float*)out)[oi] = res;
  else         ((unsigned short*)out)[oi] = f2bf(res);
}

// ---------------- host ----------------

extern "C" void kernel_launch(void* const* d_in, const int* in_sizes, int n_in,
                              void* d_out, int out_size, void* d_ws, size_t ws_size,
                              hipStream_t stream)
{
  (void)n_in; (void)out_size; (void)ws_size;
  const void* x   = d_in[0];
  const int*  ei  = (const int*)d_in[1];
  const void* ew  = d_in[2];

  const int N = in_sizes[0] / 128;
  const int E = in_sizes[2];
  const int ET = E + N;
  const int nB = (N + 255) / 256;

  char* p = (char*)d_ws;
  size_t off = 0;
  auto carve = [&](size_t bytes)->void* {
    void* r = p + off;
    off = (off + bytes + 255) & ~(size_t)255;
    return r;
  };
  int*            flag    = (int*)carve(4);
  int*            cnt     = (int*)carve((size_t)N*4);
  float*          wsum    = (float*)carve((size_t)N*4);
  int*            rowptr  = (int*)carve((size_t)(N+1)*4);
  int*            fill    = (int*)carve((size_t)N*4);
  int*            bsum    = (int*)carve((size_t)nB*4);
  int*            boff    = (int*)carve((size_t)nB*4);
  int*            csr_src = (int*)carve((size_t)ET*4);
  float*          csr_w   = (float*)carve((size_t)ET*4);
  float*          prm     = (float*)carve(15*128*4);
  unsigned short* WT0l    = (unsigned short*)carve(128*128*2);
  unsigned short* WT0r    = (unsigned short*)carve(128*128*2);
  unsigned short* WT1l    = (unsigned short*)carve(128*128*2);
  unsigned short* WT1r    = (unsigned short*)carve(128*128*2);
  unsigned short* WT2l    = (unsigned short*)carve(128*64*2);
  unsigned short* WT2r    = (unsigned short*)carve(128*64*2);
  unsigned short* xc      = (unsigned short*)carve((size_t)N*128*2);
  unsigned short* xlb16   = (unsigned short*)carve((size_t)N*128*2);   // bf16 xl (gathered)
  float*          xrb     = (float*)carve((size_t)N*128*4);            // f32 xr (sequential)
  unsigned short* hb      = (unsigned short*)carve((size_t)N*128*2);

  float* bl0c = prm + 0*128;  float* br0c = prm + 1*128;
  float* We0c = prm + 2*128;  float* at0c = prm + 3*128;  float* bi0c = prm + 4*128;
  float* bl1c = prm + 5*128;  float* br1c = prm + 6*128;
  float* We1c = prm + 7*128;  float* at1c = prm + 8*128;  float* bi1c = prm + 9*128;
  float* bl2c = prm + 10*128; float* br2c = prm + 11*128;
  float* We2c = prm + 12*128; float* at2c = prm + 13*128; float* bi2c = prm + 14*128;

  hipMemsetAsync(cnt,  0, (size_t)N*4, stream);
  hipMemsetAsync(wsum, 0, (size_t)N*4, stream);

  k_detect<<<1, 256, 0, stream>>>((const unsigned short*)x, flag);

  ParamTab pt;
  {
    const void* srcs[15] = { d_in[4], d_in[6], d_in[7], d_in[8], d_in[9],
                             d_in[11], d_in[13], d_in[14], d_in[15], d_in[16],
                             d_in[18], d_in[20], d_in[21], d_in[22], d_in[23] };
    float* dsts[15] = { bl0c, br0c, We0c, at0c, bi0c,
                        bl1c, br1c, We1c, at1c, bi1c,
                        bl2c, br2c, We2c, at2c, bi2c };
    int ns[15] = {128,128,128,128,128, 128,128,128,128,128, 64,64,64,64,64};
    for (int i = 0; i < 15; i++){ pt.src[i] = srcs[i]; pt.dst[i] = dsts[i]; pt.n[i] = ns[i]; }
  }
  k_canon_params<<<15, 128, 0, stream>>>(pt, flag);
  k_canon_bf16v<<<(((size_t)N*128/4)+255)/256, 256, 0, stream>>>(x, xc, N*128/4, flag);

  WTab wt;
  {
    const void* srcs[6] = { d_in[3], d_in[5], d_in[10], d_in[12], d_in[17], d_in[19] };
    unsigned short* dsts[6] = { WT0l, WT0r, WT1l, WT1r, WT2l, WT2r };
    int Ms[6] = {128, 128, 128, 128, 64, 64};
    for (int i = 0; i < 6; i++){ wt.src[i] = srcs[i]; wt.dst[i] = dsts[i]; wt.M[i] = Ms[i]; }
  }
  k_canonT<<<dim3(64, 6), 256, 0, stream>>>(wt, flag);

  // graph build
  k_hist <<<(E+255)/256, 256, 0, stream>>>(ei, ew, cnt, wsum, E, N, flag);
  k_scan1<<<nB, 256, 0, stream>>>(cnt, bsum, N);
  k_scan2<<<1, 1024, 0, stream>>>(bsum, boff, nB);
  k_scan3self<<<nB, 256, 0, stream>>>(cnt, boff, wsum, rowptr, fill, csr_src, csr_w, N);
  k_scatter<<<(E+255)/256, 256, 0, stream>>>(ei, ew, fill, csr_src, csr_w, E, N, ET, flag);

  const int rowBlocks = (N + 63) / 64;

  // layer 0
  k_gemm2<128><<<dim3(rowBlocks, 2), 64, 0, stream>>>(xc, WT0l, WT0r, bl0c, br0c, xlb16, xrb, N);
  k_edge128<<<(N+3)/4, 256, 0, stream>>>(xlb16, xrb, rowptr, csr_src, csr_w, We0c, at0c, bi0c, hb, N, ET);

  // layer 1
  k_gemm2<128><<<dim3(rowBlocks, 2), 64, 0, stream>>>(hb, WT1l, WT1r, bl1c, br1c, xlb16, xrb, N);
  k_edge128<<<(N+3)/4, 256, 0, stream>>>(xlb16, xrb, rowptr, csr_src, csr_w, We1c, at1c, bi1c, hb, N, ET);

  // layer 2
  k_gemm2<64><<<dim3(rowBlocks, 2), 64, 0, stream>>>(hb, WT2l, WT2r, bl2c, br2c, xlb16, xrb, N);
  k_edge64<<<(N+3)/4, 256, 0, stream>>>(xlb16, xrb, rowptr, csr_src, csr_w, We2c, at2c, bi2c,
                                        d_out, N, ET, flag);
}

// Round 8
// 504.869 us; speedup vs baseline: 1.7473x; 1.0681x over previous
//
#include <hip/hip_runtime.h>
#include <cstdint>
#include <cstddef>

typedef __bf16 bf16x8 __attribute__((ext_vector_type(8)));
typedef float f32x4 __attribute__((ext_vector_type(4)));

__device__ __forceinline__ float bf2f(unsigned short u){
  unsigned int x = ((unsigned int)u) << 16;
  return __builtin_bit_cast(float, x);
}
__device__ __forceinline__ unsigned short f2bf(float f){
  unsigned int x = __builtin_bit_cast(unsigned int, f);
  x += 0x7fffu + ((x >> 16) & 1u);
  return (unsigned short)(x >> 16);
}

// ---- DS-free cross-lane helpers: readlane (VALU) + DPP reductions ----
__device__ __forceinline__ int rl_i(int v, int l){ return __builtin_amdgcn_readlane(v, l); }
__device__ __forceinline__ float rl_f(float v, int l){
  return __builtin_bit_cast(float, __builtin_amdgcn_readlane(__builtin_bit_cast(int, v), l));
}
template<int C> __device__ __forceinline__ float dpp_add(float x){
  int y = __builtin_amdgcn_update_dpp(0, __builtin_bit_cast(int, x), C, 0xF, 0xF, true);
  return x + __builtin_bit_cast(float, y);
}
__device__ __forceinline__ float sum16(float x){
  x = dpp_add<0xB1>(x);    // quad_perm [1,0,3,2]
  x = dpp_add<0x4E>(x);    // quad_perm [2,3,0,1]
  x = dpp_add<0x124>(x);   // row_ror:4
  x = dpp_add<0x128>(x);   // row_ror:8
  return x;
}
__device__ __forceinline__ float sum64(float x){
  x = sum16(x);
  return (rl_f(x, 0) + rl_f(x, 16)) + (rl_f(x, 32) + rl_f(x, 48));
}

__device__ __forceinline__ float load_w(const void* ew, int e, int f){
  return f ? ((const float*)ew)[e] : bf2f(((const unsigned short*)ew)[e]);
}

// ---------------- dtype detect + canonicalize ----------------
__global__ void k_detect(const unsigned short* __restrict__ xs, int* __restrict__ flag){
  __shared__ int found;
  if (threadIdx.x == 0) found = 0;
  __syncthreads();
  for (int i = threadIdx.x; i < 4096; i += 256){
    unsigned short u = xs[i];
    int expo = (u >> 7) & 0xFF;
    if (expo >= 0xC0) atomicOr(&found, 1);
  }
  __syncthreads();
  if (threadIdx.x == 0) flag[0] = found;
}

struct ParamTab {
  const void* src[15];
  float*      dst[15];
  int         n[15];
};
__global__ void k_canon_params(ParamTab t, const int* __restrict__ flag){
  int b = blockIdx.x, i = threadIdx.x;
  if (i < t.n[b]){
    t.dst[b][i] = flag[0] ? ((const float*)t.src[b])[i]
                          : bf2f(((const unsigned short*)t.src[b])[i]);
  }
}

__global__ void k_canon_bf16v(const void* __restrict__ src, unsigned short* __restrict__ dst,
                              int n4, const int* __restrict__ flag){
  int i = blockIdx.x*256 + threadIdx.x;
  if (i < n4){
    if (flag[0]){
      float4 v = ((const float4*)src)[i];
      ushort4 o;
      o.x = f2bf(v.x); o.y = f2bf(v.y); o.z = f2bf(v.z); o.w = f2bf(v.w);
      ((ushort4*)dst)[i] = o;
    } else {
      ((ushort4*)dst)[i] = ((const ushort4*)src)[i];
    }
  }
}

struct WTab {
  const void* src[6];
  unsigned short* dst[6];
  int M[6];
};
__global__ void k_canonT(WTab t, const int* __restrict__ flag){
  int b = blockIdx.y;
  int M = t.M[b];
  int idx = blockIdx.x*256 + threadIdx.x;
  if (idx < 128*M){
    int k = idx / M, m = idx % M;
    unsigned short v = flag[0] ? f2bf(((const float*)t.src[b])[idx])
                               : ((const unsigned short*)t.src[b])[idx];
    t.dst[b][m*128 + k] = v;
  }
}

// ---------------- graph build ----------------

// count-only histogram: 1 atomic per edge (wsum computed later from CSR, atomic-free)
__global__ void k_hist(const int* __restrict__ ei, int* __restrict__ cnt, int E, int n){
  int e = blockIdx.x*256 + threadIdx.x;
  if (e < E){
    int d = ei[E + e];
    if ((unsigned)d < (unsigned)n) atomicAdd(&cnt[d], 1);
  }
}

__global__ void k_scan1(const int* __restrict__ cnt, int* __restrict__ bsum, int n){
  int i = blockIdx.x*256 + threadIdx.x;
  int lane = threadIdx.x & 63, w = threadIdx.x >> 6;
  int v = (i < n) ? cnt[i] + 1 : 0;
  for (int off = 32; off; off >>= 1) v += __shfl_down(v, off);
  __shared__ int ws[4];
  if (lane == 0) ws[w] = v;
  __syncthreads();
  if (threadIdx.x == 0) bsum[blockIdx.x] = ws[0] + ws[1] + ws[2] + ws[3];
}

__global__ void k_scan2(const int* __restrict__ bsum, int* __restrict__ boff, int B){
  int tid = threadIdx.x, lane = tid & 63, w = tid >> 6;
  __shared__ int ws[16];
  int v = (tid < B) ? bsum[tid] : 0;
  int sv = v;
  for (int off = 1; off < 64; off <<= 1){
    int t = __shfl_up(sv, off);
    if (lane >= off) sv += t;
  }
  if (lane == 63) ws[w] = sv;
  __syncthreads();
  if (tid == 0){
    int acc = 0;
    for (int k = 0; k < 16; k++){ int t = ws[k]; ws[k] = acc; acc += t; }
  }
  __syncthreads();
  if (tid < B) boff[tid] = ws[w] + sv - v;
}

__global__ void k_scan3(const int* __restrict__ cnt, const int* __restrict__ boff,
                        int* __restrict__ rowptr, int* __restrict__ fill, int n){
  int b = blockIdx.x, tid = threadIdx.x;
  int i = b*256 + tid;
  int lane = tid & 63, w = tid >> 6;
  __shared__ int ws[4];
  int v = (i < n) ? cnt[i] + 1 : 0;
  int sv = v;
  for (int off = 1; off < 64; off <<= 1){
    int t = __shfl_up(sv, off);
    if (lane >= off) sv += t;
  }
  if (lane == 63) ws[w] = sv;
  __syncthreads();
  if (tid == 0){
    int acc = 0;
    for (int k = 0; k < 4; k++){ int t = ws[k]; ws[k] = acc; acc += t; }
  }
  __syncthreads();
  if (i < n){
    int vend = boff[b] + ws[w] + sv;   // rowptr[i+1]
    rowptr[i + 1] = vend;
    fill[i] = vend - v;                // rowptr[i]
  }
  if (i == 0) rowptr[0] = 0;
}

// packed CSR entry: .x = src, .y = float bits of weight — one 8B store per edge
__global__ void k_scatter(const int* __restrict__ ei, const void* __restrict__ ew,
                          int* __restrict__ fill, uint2* __restrict__ csr,
                          int E, int n, int ET, const int* __restrict__ flag){
  int e = blockIdx.x*256 + threadIdx.x;
  if (e < E){
    int s = ei[e], d = ei[E + e];
    if ((unsigned)d < (unsigned)n){
      int pos = atomicAdd(&fill[d], 1);
      if ((unsigned)pos < (unsigned)ET){
        float w = load_w(ew, e, flag[0]);
        csr[pos] = make_uint2((unsigned)s, __builtin_bit_cast(unsigned, w));
      }
    }
  }
}

// per-node: sum weights over own segment (atomic-free), write self-loop in last slot
__global__ void k_selfw(const int* __restrict__ rowptr, uint2* __restrict__ csr, int n){
  int i = blockIdx.x*256 + threadIdx.x;
  if (i < n){
    int beg = rowptr[i], endv = rowptr[i+1];
    int deg = endv - 1 - beg;
    float ws = 0.f;
    for (int j = beg; j < endv - 1; j++)
      ws += __builtin_bit_cast(float, csr[j].y);
    float w = ws / fmaxf((float)deg, 1.0f);
    csr[endv - 1] = make_uint2((unsigned)i, __builtin_bit_cast(unsigned, w));
  }
}

// ---------------- GEMM: xl (bf16 out) and xr (f32 out) in one launch ----------------

template<int NC>
__global__ __launch_bounds__(64) void k_gemm2(
  const unsigned short* __restrict__ A,
  const unsigned short* __restrict__ WTl, const unsigned short* __restrict__ WTr,
  const float* __restrict__ bl, const float* __restrict__ br,
  unsigned short* __restrict__ outL, float* __restrict__ outR,
  int nrows)
{
  constexpr int CT = NC / 16;
  int lane = threadIdx.x;
  int q = lane >> 4, rr = lane & 15;
  int r0 = blockIdx.x * 64;
  bool isR = blockIdx.y == 1;
  const unsigned short* WT = isR ? WTr : WTl;
  const float* bia         = isR ? br  : bl;

  f32x4 acc[4][CT];
  for (int a = 0; a < 4; a++)
    for (int b = 0; b < CT; b++)
      acc[a][b] = (f32x4){0.f, 0.f, 0.f, 0.f};

  for (int kc = 0; kc < 4; kc++){
    bf16x8 af[4], bfr[CT];
    #pragma unroll
    for (int rt = 0; rt < 4; rt++){
      int row = r0 + rt*16 + rr;
      if (row >= nrows) row = nrows - 1;
      af[rt] = *(const bf16x8*)(A + (size_t)row*128 + kc*32 + q*8);
    }
    #pragma unroll
    for (int ct = 0; ct < CT; ct++)
      bfr[ct] = *(const bf16x8*)(WT + (size_t)(ct*16 + rr)*128 + kc*32 + q*8);
    #pragma unroll
    for (int rt = 0; rt < 4; rt++)
      #pragma unroll
      for (int ct = 0; ct < CT; ct++)
        acc[rt][ct] = __builtin_amdgcn_mfma_f32_16x16x32_bf16(af[rt], bfr[ct], acc[rt][ct], 0, 0, 0);
  }

  // C/D layout: col = lane&15, row = (lane>>4)*4 + reg
  #pragma unroll
  for (int ct = 0; ct < CT; ct++){
    int col = ct*16 + rr;
    float bv = bia[col];
    #pragma unroll
    for (int rt = 0; rt < 4; rt++){
      #pragma unroll
      for (int t = 0; t < 4; t++){
        int row = r0 + rt*16 + q*4 + t;
        if (row < nrows){
          float v = acc[rt][ct][t] + bv;
          if (isR) outR[(size_t)row*NC + col] = v;
          else     outL[(size_t)row*NC + col] = f2bf(v);
        }
      }
    }
  }
}

// ---------------- fused edge scoring + online-softmax aggregation ----------------
// DS-free inner loop (readlane + DPP); one coalesced bf16 row gather per edge;
// packed uint2 CSR (one 8B load per lane per chunk).

__global__ __launch_bounds__(256) void k_edge128(
  const unsigned short* __restrict__ xl, const float* __restrict__ xr,
  const int* __restrict__ rowptr, const uint2* __restrict__ csr,
  const float* __restrict__ We, const float* __restrict__ att,
  const float* __restrict__ bias, unsigned short* __restrict__ out, int n, int ET)
{
  int wid = threadIdx.x >> 6;
  int lane = threadIdx.x & 63;
  int node = blockIdx.x*4 + wid;
  if (node >= n) return;
  int ch = lane*2;
  float we0 = We[ch],  we1 = We[ch+1];
  float at0 = att[ch], at1 = att[ch+1];
  float2 xrv = *(const float2*)(xr + (size_t)node*128 + ch);
  float fxr0 = xrv.x, fxr1 = xrv.y;
  const unsigned short* xlc = xl + ch;
  int beg = rowptr[node], end = rowptr[node+1];
  if (beg < 0) beg = 0;
  if (end > ET) end = ET;
  float m = -1e30f, l = 0.f, a0 = 0.f, a1 = 0.f;

  for (int base = beg; base < end; base += 64){
    int idx = base + lane;
    int   sv = 0; float wv = 0.f;
    if (idx < end){
      uint2 pk = csr[idx];
      sv = (int)pk.x;
      wv = __builtin_bit_cast(float, pk.y);
    }
    if ((unsigned)sv >= (unsigned)n) sv = 0;
    int c = end - base; if (c > 64) c = 64;
    int i = 0;
    for (; i + 4 <= c; i += 4){
      int   s0 = rl_i(sv, i),   s1 = rl_i(sv, i+1),
            s2 = rl_i(sv, i+2), s3 = rl_i(sv, i+3);
      float w0 = rl_f(wv, i),   w1 = rl_f(wv, i+1),
            w2 = rl_f(wv, i+2), w3 = rl_f(wv, i+3);
      unsigned int u0 = *(const unsigned int*)(xlc + (size_t)s0*128);
      unsigned int u1 = *(const unsigned int*)(xlc + (size_t)s1*128);
      unsigned int u2 = *(const unsigned int*)(xlc + (size_t)s2*128);
      unsigned int u3 = *(const unsigned int*)(xlc + (size_t)s3*128);
      float v0x = bf2f((unsigned short)(u0 & 0xffffu)), v0y = bf2f((unsigned short)(u0 >> 16));
      float v1x = bf2f((unsigned short)(u1 & 0xffffu)), v1y = bf2f((unsigned short)(u1 >> 16));
      float v2x = bf2f((unsigned short)(u2 & 0xffffu)), v2y = bf2f((unsigned short)(u2 >> 16));
      float v3x = bf2f((unsigned short)(u3 & 0xffffu)), v3y = bf2f((unsigned short)(u3 >> 16));
      float p0, p1, p2, p3;
      {
        float t0 = v0x + fxr0 + w0*we0, t1 = v0y + fxr1 + w0*we1;
        t0 = t0 > 0.f ? t0 : 0.2f*t0;  t1 = t1 > 0.f ? t1 : 0.2f*t1;
        p0 = t0*at0 + t1*at1;
      }{
        float t0 = v1x + fxr0 + w1*we0, t1 = v1y + fxr1 + w1*we1;
        t0 = t0 > 0.f ? t0 : 0.2f*t0;  t1 = t1 > 0.f ? t1 : 0.2f*t1;
        p1 = t0*at0 + t1*at1;
      }{
        float t0 = v2x + fxr0 + w2*we0, t1 = v2y + fxr1 + w2*we1;
        t0 = t0 > 0.f ? t0 : 0.2f*t0;  t1 = t1 > 0.f ? t1 : 0.2f*t1;
        p2 = t0*at0 + t1*at1;
      }{
        float t0 = v3x + fxr0 + w3*we0, t1 = v3y + fxr1 + w3*we1;
        t0 = t0 > 0.f ? t0 : 0.2f*t0;  t1 = t1 > 0.f ? t1 : 0.2f*t1;
        p3 = t0*at0 + t1*at1;
      }
      p0 = sum16(p0); p1 = sum16(p1); p2 = sum16(p2); p3 = sum16(p3);
      float mx = fmaxf(fmaxf(p0, p1), fmaxf(p2, p3));
      float nm = fmaxf(m, mx);
      float sc = __expf(m - nm);
      float e0 = __expf(p0 - nm), e1 = __expf(p1 - nm);
      float e2 = __expf(p2 - nm), e3 = __expf(p3 - nm);
      l  = l*sc  + ((e0 + e1) + (e2 + e3));
      a0 = a0*sc + ((e0*v0x + e1*v1x) + (e2*v2x + e3*v3x));
      a1 = a1*sc + ((e0*v0y + e1*v1y) + (e2*v2y + e3*v3y));
      m = nm;
    }
    for (; i < c; i++){
      int   s = rl_i(sv, i);
      float w = rl_f(wv, i);
      unsigned int u = *(const unsigned int*)(xlc + (size_t)s*128);
      float x0 = bf2f((unsigned short)(u & 0xffffu));
      float x1 = bf2f((unsigned short)(u >> 16));
      float t0 = x0 + fxr0 + w*we0;
      float t1 = x1 + fxr1 + w*we1;
      t0 = t0 > 0.f ? t0 : 0.2f*t0;
      t1 = t1 > 0.f ? t1 : 0.2f*t1;
      float p = sum16(t0*at0 + t1*at1);
      float nm = fmaxf(m, p);
      float sc = __expf(m - nm);
      float pe = __expf(p - nm);
      l  = l*sc  + pe;
      a0 = a0*sc + pe*x0;
      a1 = a1*sc + pe*x1;
      m = nm;
    }
  }
  float inv = 1.0f / (l + 1e-16f);
  float o0 = a0*inv + bias[ch];
  float o1 = a1*inv + bias[ch+1];
  o0 = o0 > 0.f ? o0 : (__expf(o0) - 1.0f);   // ELU (layers 0,1)
  o1 = o1 > 0.f ? o1 : (__expf(o1) - 1.0f);
  unsigned int packed = (unsigned int)f2bf(o0) | ((unsigned int)f2bf(o1) << 16);
  *(unsigned int*)(out + (size_t)node*128 + ch) = packed;
}

__global__ __launch_bounds__(256) void k_edge64(
  const unsigned short* __restrict__ xl, const float* __restrict__ xr,
  const int* __restrict__ rowptr, const uint2* __restrict__ csr,
  const float* __restrict__ We, const float* __restrict__ att,
  const float* __restrict__ bias, void* __restrict__ out, int n, int ET,
  const int* __restrict__ flag)
{
  int wid = threadIdx.x >> 6;
  int lane = threadIdx.x & 63;
  int node = blockIdx.x*4 + wid;
  if (node >= n) return;
  float we0 = We[lane];
  float at0 = att[lane];
  float fxr0 = xr[(size_t)node*64 + lane];
  const unsigned short* xlc = xl + lane;
  int beg = rowptr[node], end = rowptr[node+1];
  if (beg < 0) beg = 0;
  if (end > ET) end = ET;
  float m = -1e30f, l = 0.f, a0 = 0.f;

  for (int base = beg; base < end; base += 64){
    int idx = base + lane;
    int   sv = 0; float wv = 0.f;
    if (idx < end){
      uint2 pk = csr[idx];
      sv = (int)pk.x;
      wv = __builtin_bit_cast(float, pk.y);
    }
    if ((unsigned)sv >= (unsigned)n) sv = 0;
    int c = end - base; if (c > 64) c = 64;
    int i = 0;
    for (; i + 4 <= c; i += 4){
      int   s0 = rl_i(sv, i),   s1 = rl_i(sv, i+1),
            s2 = rl_i(sv, i+2), s3 = rl_i(sv, i+3);
      float w0 = rl_f(wv, i),   w1 = rl_f(wv, i+1),
            w2 = rl_f(wv, i+2), w3 = rl_f(wv, i+3);
      float x0 = bf2f(xlc[(size_t)s0*64]);
      float x1 = bf2f(xlc[(size_t)s1*64]);
      float x2 = bf2f(xlc[(size_t)s2*64]);
      float x3 = bf2f(xlc[(size_t)s3*64]);
      float t0 = x0 + fxr0 + w0*we0;  t0 = t0 > 0.f ? t0 : 0.2f*t0;
      float t1 = x1 + fxr0 + w1*we0;  t1 = t1 > 0.f ? t1 : 0.2f*t1;
      float t2 = x2 + fxr0 + w2*we0;  t2 = t2 > 0.f ? t2 : 0.2f*t2;
      float t3 = x3 + fxr0 + w3*we0;  t3 = t3 > 0.f ? t3 : 0.2f*t3;
      float p0 = sum64(t0*at0);
      float p1 = sum64(t1*at0);
      float p2 = sum64(t2*at0);
      float p3 = sum64(t3*at0);
      float mx = fmaxf(fmaxf(p0, p1), fmaxf(p2, p3));
      float nm = fmaxf(m, mx);
      float sc = __expf(m - nm);
      float e0 = __expf(p0 - nm), e1 = __expf(p1 - nm);
      float e2 = __expf(p2 - nm), e3 = __expf(p3 - nm);
      l  = l*sc  + ((e0 + e1) + (e2 + e3));
      a0 = a0*sc + ((e0*x0 + e1*x1) + (e2*x2 + e3*x3));
      m = nm;
    }
    for (; i < c; i++){
      int   s = rl_i(sv, i);
      float w = rl_f(wv, i);
      float x0 = bf2f(xlc[(size_t)s*64]);
      float t0 = x0 + fxr0 + w*we0;
      t0 = t0 > 0.f ? t0 : 0.2f*t0;
      float p = sum64(t0*at0);
      float nm = fmaxf(m, p);
      float sc = __expf(m - nm);
      float pe = __expf(p - nm);
      l  = l*sc  + pe;
      a0 = a0*sc + pe*x0;
      m = nm;
    }
  }
  float inv = 1.0f / (l + 1e-16f);
  float res = a0*inv + bias[lane];
  size_t oi = (size_t)node*64 + lane;
  if (flag[0]) ((float*)out)[oi] = res;
  else         ((unsigned short*)out)[oi] = f2bf(res);
}

// ---------------- host ----------------

extern "C" void kernel_launch(void* const* d_in, const int* in_sizes, int n_in,
                              void* d_out, int out_size, void* d_ws, size_t ws_size,
                              hipStream_t stream)
{
  (void)n_in; (void)out_size; (void)ws_size;
  const void* x   = d_in[0];
  const int*  ei  = (const int*)d_in[1];
  const void* ew  = d_in[2];

  const int N = in_sizes[0] / 128;
  const int E = in_sizes[2];
  const int ET = E + N;
  const int nB = (N + 255) / 256;

  char* p = (char*)d_ws;
  size_t off = 0;
  auto carve = [&](size_t bytes)->void* {
    void* r = p + off;
    off = (off + bytes + 255) & ~(size_t)255;
    return r;
  };
  int*            flag    = (int*)carve(4);
  int*            cnt     = (int*)carve((size_t)N*4);
  int*            rowptr  = (int*)carve((size_t)(N+1)*4);
  int*            fill    = (int*)carve((size_t)N*4);
  int*            bsum    = (int*)carve((size_t)nB*4);
  int*            boff    = (int*)carve((size_t)nB*4);
  uint2*          csr     = (uint2*)carve((size_t)ET*8);
  float*          prm     = (float*)carve(15*128*4);
  unsigned short* WT0l    = (unsigned short*)carve(128*128*2);
  unsigned short* WT0r    = (unsigned short*)carve(128*128*2);
  unsigned short* WT1l    = (unsigned short*)carve(128*128*2);
  unsigned short* WT1r    = (unsigned short*)carve(128*128*2);
  unsigned short* WT2l    = (unsigned short*)carve(128*64*2);
  unsigned short* WT2r    = (unsigned short*)carve(128*64*2);
  unsigned short* xc      = (unsigned short*)carve((size_t)N*128*2);
  unsigned short* xlb16   = (unsigned short*)carve((size_t)N*128*2);
  float*          xrb     = (float*)carve((size_t)N*128*4);
  unsigned short* hb      = (unsigned short*)carve((size_t)N*128*2);

  float* bl0c = prm + 0*128;  float* br0c = prm + 1*128;
  float* We0c = prm + 2*128;  float* at0c = prm + 3*128;  float* bi0c = prm + 4*128;
  float* bl1c = prm + 5*128;  float* br1c = prm + 6*128;
  float* We1c = prm + 7*128;  float* at1c = prm + 8*128;  float* bi1c = prm + 9*128;
  float* bl2c = prm + 10*128; float* br2c = prm + 11*128;
  float* We2c = prm + 12*128; float* at2c = prm + 13*128; float* bi2c = prm + 14*128;

  hipMemsetAsync(cnt, 0, (size_t)N*4, stream);

  k_detect<<<1, 256, 0, stream>>>((const unsigned short*)x, flag);

  ParamTab pt;
  {
    const void* srcs[15] = { d_in[4], d_in[6], d_in[7], d_in[8], d_in[9],
                             d_in[11], d_in[13], d_in[14], d_in[15], d_in[16],
                             d_in[18], d_in[20], d_in[21], d_in[22], d_in[23] };
    float* dsts[15] = { bl0c, br0c, We0c, at0c, bi0c,
                        bl1c, br1c, We1c, at1c, bi1c,
                        bl2c, br2c, We2c, at2c, bi2c };
    int ns[15] = {128,128,128,128,128, 128,128,128,128,128, 64,64,64,64,64};
    for (int i = 0; i < 15; i++){ pt.src[i] = srcs[i]; pt.dst[i] = dsts[i]; pt.n[i] = ns[i]; }
  }
  k_canon_params<<<15, 128, 0, stream>>>(pt, flag);
  k_canon_bf16v<<<(((size_t)N*128/4)+255)/256, 256, 0, stream>>>(x, xc, N*128/4, flag);

  WTab wt;
  {
    const void* srcs[6] = { d_in[3], d_in[5], d_in[10], d_in[12], d_in[17], d_in[19] };
    unsigned short* dsts[6] = { WT0l, WT0r, WT1l, WT1r, WT2l, WT2r };
    int Ms[6] = {128, 128, 128, 128, 64, 64};
    for (int i = 0; i < 6; i++){ wt.src[i] = srcs[i]; wt.dst[i] = dsts[i]; wt.M[i] = Ms[i]; }
  }
  k_canonT<<<dim3(64, 6), 256, 0, stream>>>(wt, flag);

  // graph build (1 atomic/edge hist + 1 atomic/edge scatter, packed 8B CSR)
  k_hist <<<(E+255)/256, 256, 0, stream>>>(ei, cnt, E, N);
  k_scan1<<<nB, 256, 0, stream>>>(cnt, bsum, N);
  k_scan2<<<1, 1024, 0, stream>>>(bsum, boff, nB);
  k_scan3<<<nB, 256, 0, stream>>>(cnt, boff, rowptr, fill, N);
  k_scatter<<<(E+255)/256, 256, 0, stream>>>(ei, ew, fill, csr, E, N, ET, flag);
  k_selfw<<<nB, 256, 0, stream>>>(rowptr, csr, N);

  const int rowBlocks = (N + 63) / 64;

  // layer 0
  k_gemm2<128><<<dim3(rowBlocks, 2), 64, 0, stream>>>(xc, WT0l, WT0r, bl0c, br0c, xlb16, xrb, N);
  k_edge128<<<(N+3)/4, 256, 0, stream>>>(xlb16, xrb, rowptr, csr, We0c, at0c, bi0c, hb, N, ET);

  // layer 1
  k_gemm2<128><<<dim3(rowBlocks, 2), 64, 0, stream>>>(hb, WT1l, WT1r, bl1c, br1c, xlb16, xrb, N);
  k_edge128<<<(N+3)/4, 256, 0, stream>>>(xlb16, xrb, rowptr, csr, We1c, at1c, bi1c, hb, N, ET);

  // layer 2
  k_gemm2<64><<<dim3(rowBlocks, 2), 64, 0, stream>>>(hb, WT2l, WT2r, bl2c, br2c, xlb16, xrb, N);
  k_edge64<<<(N+3)/4, 256, 0, stream>>>(xlb16, xrb, rowptr, csr, We2c, at2c, bi2c,
                                        d_out, N, ET, flag);
}

// Round 9
// 483.266 us; speedup vs baseline: 1.8254x; 1.0447x over previous
//
#include <hip/hip_runtime.h>
#include <cstdint>
#include <cstddef>

typedef __bf16 bf16x8 __attribute__((ext_vector_type(8)));
typedef float f32x4 __attribute__((ext_vector_type(4)));
typedef float f32x2 __attribute__((ext_vector_type(2)));

__device__ __forceinline__ float bf2f(unsigned short u){
  unsigned int x = ((unsigned int)u) << 16;
  return __builtin_bit_cast(float, x);
}
__device__ __forceinline__ unsigned short f2bf(float f){
  unsigned int x = __builtin_bit_cast(unsigned int, f);
  x += 0x7fffu + ((x >> 16) & 1u);
  return (unsigned short)(x >> 16);
}

// ---- DS-free cross-lane helpers: readlane (VALU) + DPP reductions ----
__device__ __forceinline__ int rl_i(int v, int l){ return __builtin_amdgcn_readlane(v, l); }
__device__ __forceinline__ float rl_f(float v, int l){
  return __builtin_bit_cast(float, __builtin_amdgcn_readlane(__builtin_bit_cast(int, v), l));
}
template<int C> __device__ __forceinline__ float dpp_add(float x){
  int y = __builtin_amdgcn_update_dpp(0, __builtin_bit_cast(int, x), C, 0xF, 0xF, true);
  return x + __builtin_bit_cast(float, y);
}
__device__ __forceinline__ float sum16(float x){
  x = dpp_add<0xB1>(x);    // quad_perm [1,0,3,2]
  x = dpp_add<0x4E>(x);    // quad_perm [2,3,0,1]
  x = dpp_add<0x124>(x);   // row_ror:4
  x = dpp_add<0x128>(x);   // row_ror:8
  return x;
}
// 64-lane sum: row sums + row_bcast15/31 (lane63 = total) + 1 readlane
__device__ __forceinline__ float sum64(float x){
  x = sum16(x);
  x = dpp_add<0x142>(x);   // row_bcast15
  x = dpp_add<0x143>(x);   // row_bcast31
  return rl_f(x, 63);
}

__device__ __forceinline__ float load_w(const void* ew, int e, int f){
  return f ? ((const float*)ew)[e] : bf2f(((const unsigned short*)ew)[e]);
}

// ---------------- dtype detect + canonicalize ----------------
__global__ void k_detect(const unsigned short* __restrict__ xs, int* __restrict__ flag){
  __shared__ int found;
  if (threadIdx.x == 0) found = 0;
  __syncthreads();
  for (int i = threadIdx.x; i < 4096; i += 256){
    unsigned short u = xs[i];
    int expo = (u >> 7) & 0xFF;
    if (expo >= 0xC0) atomicOr(&found, 1);
  }
  __syncthreads();
  if (threadIdx.x == 0) flag[0] = found;
}

struct ParamTab {
  const void* src[15];
  float*      dst[15];
  int         n[15];
  float       scale[15];   // att slots get log2(e): folds exp->exp2 in softmax
};
__global__ void k_canon_params(ParamTab t, const int* __restrict__ flag){
  int b = blockIdx.x, i = threadIdx.x;
  if (i < t.n[b]){
    float v = flag[0] ? ((const float*)t.src[b])[i]
                      : bf2f(((const unsigned short*)t.src[b])[i]);
    t.dst[b][i] = v * t.scale[b];
  }
}

__global__ void k_canon_bf16v(const void* __restrict__ src, unsigned short* __restrict__ dst,
                              int n4, const int* __restrict__ flag){
  int i = blockIdx.x*256 + threadIdx.x;
  if (i < n4){
    if (flag[0]){
      float4 v = ((const float4*)src)[i];
      ushort4 o;
      o.x = f2bf(v.x); o.y = f2bf(v.y); o.z = f2bf(v.z); o.w = f2bf(v.w);
      ((ushort4*)dst)[i] = o;
    } else {
      ((ushort4*)dst)[i] = ((const ushort4*)src)[i];
    }
  }
}

struct WTab {
  const void* src[6];
  unsigned short* dst[6];
  int M[6];
};
__global__ void k_canonT(WTab t, const int* __restrict__ flag){
  int b = blockIdx.y;
  int M = t.M[b];
  int idx = blockIdx.x*256 + threadIdx.x;
  if (idx < 128*M){
    int k = idx / M, m = idx % M;
    unsigned short v = flag[0] ? f2bf(((const float*)t.src[b])[idx])
                               : ((const unsigned short*)t.src[b])[idx];
    t.dst[b][m*128 + k] = v;
  }
}

// ---------------- graph build ----------------

// histogram + per-edge rank (old count) -> later atomic-free scatter
__global__ void k_hist(const int* __restrict__ ei, int* __restrict__ cnt,
                       int* __restrict__ rank, int E, int n){
  int e = blockIdx.x*256 + threadIdx.x;
  if (e < E){
    int d = ei[E + e];
    int r = 0;
    if ((unsigned)d < (unsigned)n) r = atomicAdd(&cnt[d], 1);
    rank[e] = r;
  }
}

__global__ void k_scan1(const int* __restrict__ cnt, int* __restrict__ bsum, int n){
  int i = blockIdx.x*256 + threadIdx.x;
  int lane = threadIdx.x & 63, w = threadIdx.x >> 6;
  int v = (i < n) ? cnt[i] + 1 : 0;
  for (int off = 32; off; off >>= 1) v += __shfl_down(v, off);
  __shared__ int ws[4];
  if (lane == 0) ws[w] = v;
  __syncthreads();
  if (threadIdx.x == 0) bsum[blockIdx.x] = ws[0] + ws[1] + ws[2] + ws[3];
}

__global__ void k_scan2(const int* __restrict__ bsum, int* __restrict__ boff, int B){
  int tid = threadIdx.x, lane = tid & 63, w = tid >> 6;
  __shared__ int ws[16];
  int v = (tid < B) ? bsum[tid] : 0;
  int sv = v;
  for (int off = 1; off < 64; off <<= 1){
    int t = __shfl_up(sv, off);
    if (lane >= off) sv += t;
  }
  if (lane == 63) ws[w] = sv;
  __syncthreads();
  if (tid == 0){
    int acc = 0;
    for (int k = 0; k < 16; k++){ int t = ws[k]; ws[k] = acc; acc += t; }
  }
  __syncthreads();
  if (tid < B) boff[tid] = ws[w] + sv - v;
}

__global__ void k_scan3(const int* __restrict__ cnt, const int* __restrict__ boff,
                        int* __restrict__ rowptr, int n){
  int b = blockIdx.x, tid = threadIdx.x;
  int i = b*256 + tid;
  int lane = tid & 63, w = tid >> 6;
  __shared__ int ws[4];
  int v = (i < n) ? cnt[i] + 1 : 0;
  int sv = v;
  for (int off = 1; off < 64; off <<= 1){
    int t = __shfl_up(sv, off);
    if (lane >= off) sv += t;
  }
  if (lane == 63) ws[w] = sv;
  __syncthreads();
  if (tid == 0){
    int acc = 0;
    for (int k = 0; k < 4; k++){ int t = ws[k]; ws[k] = acc; acc += t; }
  }
  __syncthreads();
  if (i < n) rowptr[i + 1] = boff[b] + ws[w] + sv;
  if (i == 0) rowptr[0] = 0;
}

// ATOMIC-FREE scatter: pos = rowptr[d] + rank[e]; one packed 8B store per edge
__global__ void k_scatter(const int* __restrict__ ei, const void* __restrict__ ew,
                          const int* __restrict__ rank, const int* __restrict__ rowptr,
                          uint2* __restrict__ csr,
                          int E, int n, int ET, const int* __restrict__ flag){
  int e = blockIdx.x*256 + threadIdx.x;
  if (e < E){
    int s = ei[e], d = ei[E + e];
    if ((unsigned)d < (unsigned)n){
      int pos = rowptr[d] + rank[e];
      if ((unsigned)pos < (unsigned)ET){
        float w = load_w(ew, e, flag[0]);
        csr[pos] = make_uint2((unsigned)s, __builtin_bit_cast(unsigned, w));
      }
    }
  }
}

// per-node: sum weights over own segment (atomic-free), write self-loop in last slot
__global__ void k_selfw(const int* __restrict__ rowptr, uint2* __restrict__ csr, int n){
  int i = blockIdx.x*256 + threadIdx.x;
  if (i < n){
    int beg = rowptr[i], endv = rowptr[i+1];
    int deg = endv - 1 - beg;
    float ws = 0.f;
    for (int j = beg; j < endv - 1; j++)
      ws += __builtin_bit_cast(float, csr[j].y);
    float w = ws / fmaxf((float)deg, 1.0f);
    csr[endv - 1] = make_uint2((unsigned)i, __builtin_bit_cast(unsigned, w));
  }
}

// ---------------- GEMM: xl (bf16 out) and xr (f32 out) in one launch ----------------

template<int NC>
__global__ __launch_bounds__(64) void k_gemm2(
  const unsigned short* __restrict__ A,
  const unsigned short* __restrict__ WTl, const unsigned short* __restrict__ WTr,
  const float* __restrict__ bl, const float* __restrict__ br,
  unsigned short* __restrict__ outL, float* __restrict__ outR,
  int nrows)
{
  constexpr int CT = NC / 16;
  int lane = threadIdx.x;
  int q = lane >> 4, rr = lane & 15;
  int r0 = blockIdx.x * 64;
  bool isR = blockIdx.y == 1;
  const unsigned short* WT = isR ? WTr : WTl;
  const float* bia         = isR ? br  : bl;

  f32x4 acc[4][CT];
  for (int a = 0; a < 4; a++)
    for (int b = 0; b < CT; b++)
      acc[a][b] = (f32x4){0.f, 0.f, 0.f, 0.f};

  for (int kc = 0; kc < 4; kc++){
    bf16x8 af[4], bfr[CT];
    #pragma unroll
    for (int rt = 0; rt < 4; rt++){
      int row = r0 + rt*16 + rr;
      if (row >= nrows) row = nrows - 1;
      af[rt] = *(const bf16x8*)(A + (size_t)row*128 + kc*32 + q*8);
    }
    #pragma unroll
    for (int ct = 0; ct < CT; ct++)
      bfr[ct] = *(const bf16x8*)(WT + (size_t)(ct*16 + rr)*128 + kc*32 + q*8);
    #pragma unroll
    for (int rt = 0; rt < 4; rt++)
      #pragma unroll
      for (int ct = 0; ct < CT; ct++)
        acc[rt][ct] = __builtin_amdgcn_mfma_f32_16x16x32_bf16(af[rt], bfr[ct], acc[rt][ct], 0, 0, 0);
  }

  // C/D layout: col = lane&15, row = (lane>>4)*4 + reg
  #pragma unroll
  for (int ct = 0; ct < CT; ct++){
    int col = ct*16 + rr;
    float bv = bia[col];
    #pragma unroll
    for (int rt = 0; rt < 4; rt++){
      #pragma unroll
      for (int t = 0; t < 4; t++){
        int row = r0 + rt*16 + q*4 + t;
        if (row < nrows){
          float v = acc[rt][ct][t] + bv;
          if (isR) outR[(size_t)row*NC + col] = v;
          else     outL[(size_t)row*NC + col] = f2bf(v);
        }
      }
    }
  }
}

// ---------------- fused edge scoring + online-softmax aggregation ----------------
// DS-free (readlane + DPP); packed-f32 channel math (v_pk_*); att pre-scaled by
// log2(e) so all softmax exponentials are raw v_exp_f32 (exp2f).

__global__ __launch_bounds__(256) void k_edge128(
  const unsigned short* __restrict__ xl, const float* __restrict__ xr,
  const int* __restrict__ rowptr, const uint2* __restrict__ csr,
  const float* __restrict__ We, const float* __restrict__ att,
  const float* __restrict__ bias, unsigned short* __restrict__ out, int n, int ET)
{
  int wid = threadIdx.x >> 6;
  int lane = threadIdx.x & 63;
  int node = blockIdx.x*4 + wid;
  if (node >= n) return;
  int ch = lane*2;
  f32x2 we2; we2.x = We[ch];  we2.y = We[ch+1];
  f32x2 at2; at2.x = att[ch]; at2.y = att[ch+1];    // pre-scaled by log2e
  float2 xrv = *(const float2*)(xr + (size_t)node*128 + ch);
  f32x2 fxr2; fxr2.x = xrv.x; fxr2.y = xrv.y;
  const unsigned short* xlc = xl + ch;
  int beg = rowptr[node], end = rowptr[node+1];
  if (beg < 0) beg = 0;
  if (end > ET) end = ET;
  float m = -1e30f, l = 0.f;
  f32x2 a2 = (f32x2){0.f, 0.f};

  for (int base = beg; base < end; base += 64){
    int idx = base + lane;
    int   sv = 0; float wv = 0.f;
    if (idx < end){
      uint2 pk = csr[idx];
      sv = (int)pk.x;
      wv = __builtin_bit_cast(float, pk.y);
    }
    if ((unsigned)sv >= (unsigned)n) sv = 0;
    int c = end - base; if (c > 64) c = 64;
    int i = 0;
    for (; i + 4 <= c; i += 4){
      int   s0 = rl_i(sv, i),   s1 = rl_i(sv, i+1),
            s2 = rl_i(sv, i+2), s3 = rl_i(sv, i+3);
      float w0 = rl_f(wv, i),   w1 = rl_f(wv, i+1),
            w2 = rl_f(wv, i+2), w3 = rl_f(wv, i+3);
      unsigned int u0 = *(const unsigned int*)(xlc + (size_t)s0*128);
      unsigned int u1 = *(const unsigned int*)(xlc + (size_t)s1*128);
      unsigned int u2 = *(const unsigned int*)(xlc + (size_t)s2*128);
      unsigned int u3 = *(const unsigned int*)(xlc + (size_t)s3*128);
      f32x2 v0, v1, v2, v3;
      v0.x = __builtin_bit_cast(float, u0 << 16); v0.y = __builtin_bit_cast(float, u0 & 0xffff0000u);
      v1.x = __builtin_bit_cast(float, u1 << 16); v1.y = __builtin_bit_cast(float, u1 & 0xffff0000u);
      v2.x = __builtin_bit_cast(float, u2 << 16); v2.y = __builtin_bit_cast(float, u2 & 0xffff0000u);
      v3.x = __builtin_bit_cast(float, u3 << 16); v3.y = __builtin_bit_cast(float, u3 & 0xffff0000u);
      f32x2 t0 = (v0 + fxr2) + w0*we2;
      f32x2 t1 = (v1 + fxr2) + w1*we2;
      f32x2 t2 = (v2 + fxr2) + w2*we2;
      f32x2 t3 = (v3 + fxr2) + w3*we2;
      t0 = __builtin_elementwise_max(t0, 0.2f*t0);
      t1 = __builtin_elementwise_max(t1, 0.2f*t1);
      t2 = __builtin_elementwise_max(t2, 0.2f*t2);
      t3 = __builtin_elementwise_max(t3, 0.2f*t3);
      f32x2 d0 = t0*at2, d1 = t1*at2, d2 = t2*at2, d3 = t3*at2;
      float p0 = sum16(d0.x + d0.y);
      float p1 = sum16(d1.x + d1.y);
      float p2 = sum16(d2.x + d2.y);
      float p3 = sum16(d3.x + d3.y);
      float mx = fmaxf(fmaxf(p0, p1), fmaxf(p2, p3));
      float nm = fmaxf(m, mx);
      float sc = exp2f(m - nm);
      float e0 = exp2f(p0 - nm), e1 = exp2f(p1 - nm);
      float e2 = exp2f(p2 - nm), e3 = exp2f(p3 - nm);
      l  = l*sc + ((e0 + e1) + (e2 + e3));
      a2 = a2*sc + ((e0*v0 + e1*v1) + (e2*v2 + e3*v3));
      m = nm;
    }
    for (; i < c; i++){
      int   s = rl_i(sv, i);
      float w = rl_f(wv, i);
      unsigned int u = *(const unsigned int*)(xlc + (size_t)s*128);
      f32x2 v;
      v.x = __builtin_bit_cast(float, u << 16);
      v.y = __builtin_bit_cast(float, u & 0xffff0000u);
      f32x2 t = (v + fxr2) + w*we2;
      t = __builtin_elementwise_max(t, 0.2f*t);
      f32x2 d = t*at2;
      float p = sum16(d.x + d.y);
      float nm = fmaxf(m, p);
      float sc = exp2f(m - nm);
      float pe = exp2f(p - nm);
      l  = l*sc + pe;
      a2 = a2*sc + pe*v;
      m = nm;
    }
  }
  float inv = 1.0f / (l + 1e-16f);
  float o0 = a2.x*inv + bias[ch];
  float o1 = a2.y*inv + bias[ch+1];
  o0 = o0 > 0.f ? o0 : (__expf(o0) - 1.0f);   // ELU (layers 0,1)
  o1 = o1 > 0.f ? o1 : (__expf(o1) - 1.0f);
  unsigned int packed = (unsigned int)f2bf(o0) | ((unsigned int)f2bf(o1) << 16);
  *(unsigned int*)(out + (size_t)node*128 + ch) = packed;
}

__global__ __launch_bounds__(256) void k_edge64(
  const unsigned short* __restrict__ xl, const float* __restrict__ xr,
  const int* __restrict__ rowptr, const uint2* __restrict__ csr,
  const float* __restrict__ We, const float* __restrict__ att,
  const float* __restrict__ bias, void* __restrict__ out, int n, int ET,
  const int* __restrict__ flag)
{
  int wid = threadIdx.x >> 6;
  int lane = threadIdx.x & 63;
  int node = blockIdx.x*4 + wid;
  if (node >= n) return;
  float we0 = We[lane];
  float at0 = att[lane];          // pre-scaled by log2e
  float fxr0 = xr[(size_t)node*64 + lane];
  const unsigned short* xlc = xl + lane;
  int beg = rowptr[node], end = rowptr[node+1];
  if (beg < 0) beg = 0;
  if (end > ET) end = ET;
  float m = -1e30f, l = 0.f, a0 = 0.f;

  for (int base = beg; base < end; base += 64){
    int idx = base + lane;
    int   sv = 0; float wv = 0.f;
    if (idx < end){
      uint2 pk = csr[idx];
      sv = (int)pk.x;
      wv = __builtin_bit_cast(float, pk.y);
    }
    if ((unsigned)sv >= (unsigned)n) sv = 0;
    int c = end - base; if (c > 64) c = 64;
    int i = 0;
    for (; i + 4 <= c; i += 4){
      int   s0 = rl_i(sv, i),   s1 = rl_i(sv, i+1),
            s2 = rl_i(sv, i+2), s3 = rl_i(sv, i+3);
      float w0 = rl_f(wv, i),   w1 = rl_f(wv, i+1),
            w2 = rl_f(wv, i+2), w3 = rl_f(wv, i+3);
      float x0 = bf2f(xlc[(size_t)s0*64]);
      float x1 = bf2f(xlc[(size_t)s1*64]);
      float x2 = bf2f(xlc[(size_t)s2*64]);
      float x3 = bf2f(xlc[(size_t)s3*64]);
      float t0 = x0 + fxr0 + w0*we0;  t0 = fmaxf(t0, 0.2f*t0);
      float t1 = x1 + fxr0 + w1*we0;  t1 = fmaxf(t1, 0.2f*t1);
      float t2 = x2 + fxr0 + w2*we0;  t2 = fmaxf(t2, 0.2f*t2);
      float t3 = x3 + fxr0 + w3*we0;  t3 = fmaxf(t3, 0.2f*t3);
      float p0 = sum64(t0*at0);
      float p1 = sum64(t1*at0);
      float p2 = sum64(t2*at0);
      float p3 = sum64(t3*at0);
      float mx = fmaxf(fmaxf(p0, p1), fmaxf(p2, p3));
      float nm = fmaxf(m, mx);
      float sc = exp2f(m - nm);
      float e0 = exp2f(p0 - nm), e1 = exp2f(p1 - nm);
      float e2 = exp2f(p2 - nm), e3 = exp2f(p3 - nm);
      l  = l*sc  + ((e0 + e1) + (e2 + e3));
      a0 = a0*sc + ((e0*x0 + e1*x1) + (e2*x2 + e3*x3));
      m = nm;
    }
    for (; i < c; i++){
      int   s = rl_i(sv, i);
      float w = rl_f(wv, i);
      float x0 = bf2f(xlc[(size_t)s*64]);
      float t0 = x0 + fxr0 + w*we0;
      t0 = fmaxf(t0, 0.2f*t0);
      float p = sum64(t0*at0);
      float nm = fmaxf(m, p);
      float sc = exp2f(m - nm);
      float pe = exp2f(p - nm);
      l  = l*sc  + pe;
      a0 = a0*sc + pe*x0;
      m = nm;
    }
  }
  float inv = 1.0f / (l + 1e-16f);
  float res = a0*inv + bias[lane];
  size_t oi = (size_t)node*64 + lane;
  if (flag[0]) ((float*)out)[oi] = res;
  else         ((unsigned short*)out)[oi] = f2bf(res);
}

// ---------------- host ----------------

extern "C" void kernel_launch(void* const* d_in, const int* in_sizes, int n_in,
                              void* d_out, int out_size, void* d_ws, size_t ws_size,
                              hipStream_t stream)
{
  (void)n_in; (void)out_size; (void)ws_size;
  const void* x   = d_in[0];
  const int*  ei  = (const int*)d_in[1];
  const void* ew  = d_in[2];

  const int N = in_sizes[0] / 128;
  const int E = in_sizes[2];
  const int ET = E + N;
  const int nB = (N + 255) / 256;

  char* p = (char*)d_ws;
  size_t off = 0;
  auto carve = [&](size_t bytes)->void* {
    void* r = p + off;
    off = (off + bytes + 255) & ~(size_t)255;
    return r;
  };
  int*            flag    = (int*)carve(4);
  int*            cnt     = (int*)carve((size_t)N*4);
  int*            rowptr  = (int*)carve((size_t)(N+1)*4);
  int*            bsum    = (int*)carve((size_t)nB*4);
  int*            boff    = (int*)carve((size_t)nB*4);
  int*            rank    = (int*)carve((size_t)E*4);
  uint2*          csr     = (uint2*)carve((size_t)ET*8);
  float*          prm     = (float*)carve(15*128*4);
  unsigned short* WT0l    = (unsigned short*)carve(128*128*2);
  unsigned short* WT0r    = (unsigned short*)carve(128*128*2);
  unsigned short* WT1l    = (unsigned short*)carve(128*128*2);
  unsigned short* WT1r    = (unsigned short*)carve(128*128*2);
  unsigned short* WT2l    = (unsigned short*)carve(128*64*2);
  unsigned short* WT2r    = (unsigned short*)carve(128*64*2);
  unsigned short* xc      = (unsigned short*)carve((size_t)N*128*2);
  unsigned short* xlb16   = (unsigned short*)carve((size_t)N*128*2);
  float*          xrb     = (float*)carve((size_t)N*128*4);
  unsigned short* hb      = (unsigned short*)carve((size_t)N*128*2);

  float* bl0c = prm + 0*128;  float* br0c = prm + 1*128;
  float* We0c = prm + 2*128;  float* at0c = prm + 3*128;  float* bi0c = prm + 4*128;
  float* bl1c = prm + 5*128;  float* br1c = prm + 6*128;
  float* We1c = prm + 7*128;  float* at1c = prm + 8*128;  float* bi1c = prm + 9*128;
  float* bl2c = prm + 10*128; float* br2c = prm + 11*128;
  float* We2c = prm + 12*128; float* at2c = prm + 13*128; float* bi2c = prm + 14*128;

  hipMemsetAsync(cnt, 0, (size_t)N*4, stream);

  k_detect<<<1, 256, 0, stream>>>((const unsigned short*)x, flag);

  const float LOG2E = 1.4426950408889634f;
  ParamTab pt;
  {
    const void* srcs[15] = { d_in[4], d_in[6], d_in[7], d_in[8], d_in[9],
                             d_in[11], d_in[13], d_in[14], d_in[15], d_in[16],
                             d_in[18], d_in[20], d_in[21], d_in[22], d_in[23] };
    float* dsts[15] = { bl0c, br0c, We0c, at0c, bi0c,
                        bl1c, br1c, We1c, at1c, bi1c,
                        bl2c, br2c, We2c, at2c, bi2c };
    int ns[15] = {128,128,128,128,128, 128,128,128,128,128, 64,64,64,64,64};
    for (int i = 0; i < 15; i++){
      pt.src[i] = srcs[i]; pt.dst[i] = dsts[i]; pt.n[i] = ns[i];
      pt.scale[i] = (i == 3 || i == 8 || i == 13) ? LOG2E : 1.0f;  // att slots
    }
  }
  k_canon_params<<<15, 128, 0, stream>>>(pt, flag);
  k_canon_bf16v<<<(((size_t)N*128/4)+255)/256, 256, 0, stream>>>(x, xc, N*128/4, flag);

  WTab wt;
  {
    const void* srcs[6] = { d_in[3], d_in[5], d_in[10], d_in[12], d_in[17], d_in[19] };
    unsigned short* dsts[6] = { WT0l, WT0r, WT1l, WT1r, WT2l, WT2r };
    int Ms[6] = {128, 128, 128, 128, 64, 64};
    for (int i = 0; i < 6; i++){ wt.src[i] = srcs[i]; wt.dst[i] = dsts[i]; wt.M[i] = Ms[i]; }
  }
  k_canonT<<<dim3(64, 6), 256, 0, stream>>>(wt, flag);

  // graph build: 1 atomic/edge (hist+rank), then atomic-free scatter
  k_hist <<<(E+255)/256, 256, 0, stream>>>(ei, cnt, rank, E, N);
  k_scan1<<<nB, 256, 0, stream>>>(cnt, bsum, N);
  k_scan2<<<1, 1024, 0, stream>>>(bsum, boff, nB);
  k_scan3<<<nB, 256, 0, stream>>>(cnt, boff, rowptr, N);
  k_scatter<<<(E+255)/256, 256, 0, stream>>>(ei, ew, rank, rowptr, csr, E, N, ET, flag);
  k_selfw<<<nB, 256, 0, stream>>>(rowptr, csr, N);

  const int rowBlocks = (N + 63) / 64;

  // layer 0
  k_gemm2<128><<<dim3(rowBlocks, 2), 64, 0, stream>>>(xc, WT0l, WT0r, bl0c, br0c, xlb16, xrb, N);
  k_edge128<<<(N+3)/4, 256, 0, stream>>>(xlb16, xrb, rowptr, csr, We0c, at0c, bi0c, hb, N, ET);

  // layer 1
  k_gemm2<128><<<dim3(rowBlocks, 2), 64, 0, stream>>>(hb, WT1l, WT1r, bl1c, br1c, xlb16, xrb, N);
  k_edge128<<<(N+3)/4, 256, 0, stream>>>(xlb16, xrb, rowptr, csr, We1c, at1c, bi1c, hb, N, ET);

  // layer 2
  k_gemm2<64><<<dim3(rowBlocks, 2), 64, 0, stream>>>(hb, WT2l, WT2r, bl2c, br2c, xlb16, xrb, N);
  k_edge64<<<(N+3)/4, 256, 0, stream>>>(xlb16, xrb, rowptr, csr, We2c, at2c, bi2c,
                                        d_out, N, ET, flag);
}

// Round 10
// 477.847 us; speedup vs baseline: 1.8461x; 1.0113x over previous
//
#include <hip/hip_runtime.h>
#include <cstdint>
#include <cstddef>

typedef __bf16 bf16x8 __attribute__((ext_vector_type(8)));
typedef float f32x4 __attribute__((ext_vector_type(4)));

__device__ __forceinline__ float bf2f(unsigned short u){
  unsigned int x = ((unsigned int)u) << 16;
  return __builtin_bit_cast(float, x);
}
__device__ __forceinline__ unsigned short f2bf(float f){
  unsigned int x = __builtin_bit_cast(unsigned int, f);
  x += 0x7fffu + ((x >> 16) & 1u);
  return (unsigned short)(x >> 16);
}

// ---- DS-free cross-lane helpers: readlane (VALU) + DPP reductions ----
__device__ __forceinline__ int rl_i(int v, int l){ return __builtin_amdgcn_readlane(v, l); }
__device__ __forceinline__ float rl_f(float v, int l){
  return __builtin_bit_cast(float, __builtin_amdgcn_readlane(__builtin_bit_cast(int, v), l));
}
template<int C> __device__ __forceinline__ float dpp_add(float x){
  int y = __builtin_amdgcn_update_dpp(0, __builtin_bit_cast(int, x), C, 0xF, 0xF, true);
  return x + __builtin_bit_cast(float, y);
}
__device__ __forceinline__ float sum16(float x){
  x = dpp_add<0xB1>(x);    // quad_perm [1,0,3,2]
  x = dpp_add<0x4E>(x);    // quad_perm [2,3,0,1]
  x = dpp_add<0x124>(x);   // row_ror:4
  x = dpp_add<0x128>(x);   // row_ror:8
  return x;
}
__device__ __forceinline__ float sum64(float x){
  x = sum16(x);
  x = dpp_add<0x142>(x);   // row_bcast15
  x = dpp_add<0x143>(x);   // row_bcast31
  return rl_f(x, 63);
}

__device__ __forceinline__ float load_w(const void* ew, int e, int f){
  return f ? ((const float*)ew)[e] : bf2f(((const unsigned short*)ew)[e]);
}

// ---------------- dtype detect + canonicalize ----------------
__global__ void k_detect(const unsigned short* __restrict__ xs, int* __restrict__ flag){
  __shared__ int found;
  if (threadIdx.x == 0) found = 0;
  __syncthreads();
  for (int i = threadIdx.x; i < 4096; i += 256){
    unsigned short u = xs[i];
    int expo = (u >> 7) & 0xFF;
    if (expo >= 0xC0) atomicOr(&found, 1);
  }
  __syncthreads();
  if (threadIdx.x == 0) flag[0] = found;
}

struct ParamTab {
  const void* src[15];
  float*      dst[15];
  int         n[15];
  float       scale[15];   // att slots get log2(e): folds exp->exp2 in softmax
};
__global__ void k_canon_params(ParamTab t, const int* __restrict__ flag){
  int b = blockIdx.x, i = threadIdx.x;
  if (i < t.n[b]){
    float v = flag[0] ? ((const float*)t.src[b])[i]
                      : bf2f(((const unsigned short*)t.src[b])[i]);
    t.dst[b][i] = v * t.scale[b];
  }
}

__global__ void k_canon_bf16v(const void* __restrict__ src, unsigned short* __restrict__ dst,
                              int n4, const int* __restrict__ flag){
  int i = blockIdx.x*256 + threadIdx.x;
  if (i < n4){
    if (flag[0]){
      float4 v = ((const float4*)src)[i];
      ushort4 o;
      o.x = f2bf(v.x); o.y = f2bf(v.y); o.z = f2bf(v.z); o.w = f2bf(v.w);
      ((ushort4*)dst)[i] = o;
    } else {
      ((ushort4*)dst)[i] = ((const ushort4*)src)[i];
    }
  }
}

struct WTab {
  const void* src[6];
  unsigned short* dst[6];
  int M[6];
};
__global__ void k_canonT(WTab t, const int* __restrict__ flag){
  int b = blockIdx.y;
  int M = t.M[b];
  int idx = blockIdx.x*256 + threadIdx.x;
  if (idx < 128*M){
    int k = idx / M, m = idx % M;
    unsigned short v = flag[0] ? f2bf(((const float*)t.src[b])[idx])
                               : ((const unsigned short*)t.src[b])[idx];
    t.dst[b][m*128 + k] = v;
  }
}

// ---------------- graph build ----------------

__global__ void k_hist(const int* __restrict__ ei, int* __restrict__ cnt,
                       int* __restrict__ rank, int E, int n){
  int e = blockIdx.x*256 + threadIdx.x;
  if (e < E){
    int d = ei[E + e];
    int r = 0;
    if ((unsigned)d < (unsigned)n) r = atomicAdd(&cnt[d], 1);
    rank[e] = r;
  }
}

__global__ void k_scan1(const int* __restrict__ cnt, int* __restrict__ bsum, int n){
  int i = blockIdx.x*256 + threadIdx.x;
  int lane = threadIdx.x & 63, w = threadIdx.x >> 6;
  int v = (i < n) ? cnt[i] + 1 : 0;
  for (int off = 32; off; off >>= 1) v += __shfl_down(v, off);
  __shared__ int ws[4];
  if (lane == 0) ws[w] = v;
  __syncthreads();
  if (threadIdx.x == 0) bsum[blockIdx.x] = ws[0] + ws[1] + ws[2] + ws[3];
}

__global__ void k_scan2(const int* __restrict__ bsum, int* __restrict__ boff, int B){
  int tid = threadIdx.x, lane = tid & 63, w = tid >> 6;
  __shared__ int ws[16];
  int v = (tid < B) ? bsum[tid] : 0;
  int sv = v;
  for (int off = 1; off < 64; off <<= 1){
    int t = __shfl_up(sv, off);
    if (lane >= off) sv += t;
  }
  if (lane == 63) ws[w] = sv;
  __syncthreads();
  if (tid == 0){
    int acc = 0;
    for (int k = 0; k < 16; k++){ int t = ws[k]; ws[k] = acc; acc += t; }
  }
  __syncthreads();
  if (tid < B) boff[tid] = ws[w] + sv - v;
}

__global__ void k_scan3(const int* __restrict__ cnt, const int* __restrict__ boff,
                        int* __restrict__ rowptr, int n){
  int b = blockIdx.x, tid = threadIdx.x;
  int i = b*256 + tid;
  int lane = tid & 63, w = tid >> 6;
  __shared__ int ws[4];
  int v = (i < n) ? cnt[i] + 1 : 0;
  int sv = v;
  for (int off = 1; off < 64; off <<= 1){
    int t = __shfl_up(sv, off);
    if (lane >= off) sv += t;
  }
  if (lane == 63) ws[w] = sv;
  __syncthreads();
  if (tid == 0){
    int acc = 0;
    for (int k = 0; k < 4; k++){ int t = ws[k]; ws[k] = acc; acc += t; }
  }
  __syncthreads();
  if (i < n) rowptr[i + 1] = boff[b] + ws[w] + sv;
  if (i == 0) rowptr[0] = 0;
}

// ATOMIC-FREE scatter: pos = rowptr[d] + rank[e]; one packed 8B store per edge
__global__ void k_scatter(const int* __restrict__ ei, const void* __restrict__ ew,
                          const int* __restrict__ rank, const int* __restrict__ rowptr,
                          uint2* __restrict__ csr,
                          int E, int n, int ET, const int* __restrict__ flag){
  int e = blockIdx.x*256 + threadIdx.x;
  if (e < E){
    int s = ei[e], d = ei[E + e];
    if ((unsigned)d < (unsigned)n){
      int pos = rowptr[d] + rank[e];
      if ((unsigned)pos < (unsigned)ET){
        float w = load_w(ew, e, flag[0]);
        csr[pos] = make_uint2((unsigned)s, __builtin_bit_cast(unsigned, w));
      }
    }
  }
}

// per-node: sum weights over own segment (atomic-free), write self-loop in last slot
__global__ void k_selfw(const int* __restrict__ rowptr, uint2* __restrict__ csr, int n){
  int i = blockIdx.x*256 + threadIdx.x;
  if (i < n){
    int beg = rowptr[i], endv = rowptr[i+1];
    int deg = endv - 1 - beg;
    float ws = 0.f;
    for (int j = beg; j < endv - 1; j++)
      ws += __builtin_bit_cast(float, csr[j].y);
    float w = ws / fmaxf((float)deg, 1.0f);
    csr[endv - 1] = make_uint2((unsigned)i, __builtin_bit_cast(unsigned, w));
  }
}

// ---------------- GEMM: xl (bf16 out) and xr (f32 out) in one launch ----------------

template<int NC>
__global__ __launch_bounds__(64) void k_gemm2(
  const unsigned short* __restrict__ A,
  const unsigned short* __restrict__ WTl, const unsigned short* __restrict__ WTr,
  const float* __restrict__ bl, const float* __restrict__ br,
  unsigned short* __restrict__ outL, float* __restrict__ outR,
  int nrows)
{
  constexpr int CT = NC / 16;
  int lane = threadIdx.x;
  int q = lane >> 4, rr = lane & 15;
  int r0 = blockIdx.x * 64;
  bool isR = blockIdx.y == 1;
  const unsigned short* WT = isR ? WTr : WTl;
  const float* bia         = isR ? br  : bl;

  f32x4 acc[4][CT];
  for (int a = 0; a < 4; a++)
    for (int b = 0; b < CT; b++)
      acc[a][b] = (f32x4){0.f, 0.f, 0.f, 0.f};

  for (int kc = 0; kc < 4; kc++){
    bf16x8 af[4], bfr[CT];
    #pragma unroll
    for (int rt = 0; rt < 4; rt++){
      int row = r0 + rt*16 + rr;
      if (row >= nrows) row = nrows - 1;
      af[rt] = *(const bf16x8*)(A + (size_t)row*128 + kc*32 + q*8);
    }
    #pragma unroll
    for (int ct = 0; ct < CT; ct++)
      bfr[ct] = *(const bf16x8*)(WT + (size_t)(ct*16 + rr)*128 + kc*32 + q*8);
    #pragma unroll
    for (int rt = 0; rt < 4; rt++)
      #pragma unroll
      for (int ct = 0; ct < CT; ct++)
        acc[rt][ct] = __builtin_amdgcn_mfma_f32_16x16x32_bf16(af[rt], bfr[ct], acc[rt][ct], 0, 0, 0);
  }

  // C/D layout: col = lane&15, row = (lane>>4)*4 + reg
  #pragma unroll
  for (int ct = 0; ct < CT; ct++){
    int col = ct*16 + rr;
    float bv = bia[col];
    #pragma unroll
    for (int rt = 0; rt < 4; rt++){
      #pragma unroll
      for (int t = 0; t < 4; t++){
        int row = r0 + rt*16 + q*4 + t;
        if (row < nrows){
          float v = acc[rt][ct][t] + bv;
          if (isR) outR[(size_t)row*NC + col] = v;
          else     outL[(size_t)row*NC + col] = f2bf(v);
        }
      }
    }
  }
}

// ---------------- fused edge scoring + online-softmax aggregation ----------------
// DS-free (readlane + DPP); scalar channel math (round-8 proven form); exp2
// softmax (att pre-scaled by log2e); 8-wide unroll for gather MLP.

__global__ __launch_bounds__(256) void k_edge128(
  const unsigned short* __restrict__ xl, const float* __restrict__ xr,
  const int* __restrict__ rowptr, const uint2* __restrict__ csr,
  const float* __restrict__ We, const float* __restrict__ att,
  const float* __restrict__ bias, unsigned short* __restrict__ out, int n, int ET)
{
  int wid = threadIdx.x >> 6;
  int lane = threadIdx.x & 63;
  int node = blockIdx.x*4 + wid;
  if (node >= n) return;
  int ch = lane*2;
  float we0 = We[ch],  we1 = We[ch+1];
  float at0 = att[ch], at1 = att[ch+1];   // pre-scaled by log2e
  float2 xrv = *(const float2*)(xr + (size_t)node*128 + ch);
  float fxr0 = xrv.x, fxr1 = xrv.y;
  const unsigned short* xlc = xl + ch;
  int beg = rowptr[node], end = rowptr[node+1];
  if (beg < 0) beg = 0;
  if (end > ET) end = ET;
  float m = -1e30f, l = 0.f, a0 = 0.f, a1 = 0.f;

  for (int base = beg; base < end; base += 64){
    int idx = base + lane;
    int   sv = 0; float wv = 0.f;
    if (idx < end){
      uint2 pk = csr[idx];
      sv = (int)pk.x;
      wv = __builtin_bit_cast(float, pk.y);
    }
    if ((unsigned)sv >= (unsigned)n) sv = 0;
    int c = end - base; if (c > 64) c = 64;
    int i = 0;
    for (; i + 8 <= c; i += 8){
      unsigned int u[8]; float w[8];
      #pragma unroll
      for (int j = 0; j < 8; j++){
        int s = rl_i(sv, i + j);
        w[j] = rl_f(wv, i + j);
        u[j] = *(const unsigned int*)(xlc + (size_t)s*128);
      }
      float vx[8], vy[8], pp[8];
      #pragma unroll
      for (int j = 0; j < 8; j++){
        vx[j] = __builtin_bit_cast(float, u[j] << 16);
        vy[j] = __builtin_bit_cast(float, u[j] & 0xffff0000u);
        float t0 = vx[j] + fxr0 + w[j]*we0;
        float t1 = vy[j] + fxr1 + w[j]*we1;
        t0 = fmaxf(t0, 0.2f*t0);
        t1 = fmaxf(t1, 0.2f*t1);
        pp[j] = sum16(t0*at0 + t1*at1);
      }
      float mx = fmaxf(fmaxf(fmaxf(pp[0], pp[1]), fmaxf(pp[2], pp[3])),
                       fmaxf(fmaxf(pp[4], pp[5]), fmaxf(pp[6], pp[7])));
      float nm = fmaxf(m, mx);
      float sc = exp2f(m - nm);
      float el = 0.f, ea0 = 0.f, ea1 = 0.f;
      #pragma unroll
      for (int j = 0; j < 8; j++){
        float e = exp2f(pp[j] - nm);
        el  += e;
        ea0 += e*vx[j];
        ea1 += e*vy[j];
      }
      l  = l*sc  + el;
      a0 = a0*sc + ea0;
      a1 = a1*sc + ea1;
      m = nm;
    }
    for (; i < c; i++){
      int   s = rl_i(sv, i);
      float w = rl_f(wv, i);
      unsigned int u = *(const unsigned int*)(xlc + (size_t)s*128);
      float x0 = __builtin_bit_cast(float, u << 16);
      float x1 = __builtin_bit_cast(float, u & 0xffff0000u);
      float t0 = x0 + fxr0 + w*we0;
      float t1 = x1 + fxr1 + w*we1;
      t0 = fmaxf(t0, 0.2f*t0);
      t1 = fmaxf(t1, 0.2f*t1);
      float p = sum16(t0*at0 + t1*at1);
      float nm = fmaxf(m, p);
      float sc = exp2f(m - nm);
      float pe = exp2f(p - nm);
      l  = l*sc  + pe;
      a0 = a0*sc + pe*x0;
      a1 = a1*sc + pe*x1;
      m = nm;
    }
  }
  float inv = 1.0f / (l + 1e-16f);
  float o0 = a0*inv + bias[ch];
  float o1 = a1*inv + bias[ch+1];
  o0 = o0 > 0.f ? o0 : (__expf(o0) - 1.0f);   // ELU (layers 0,1)
  o1 = o1 > 0.f ? o1 : (__expf(o1) - 1.0f);
  unsigned int packed = (unsigned int)f2bf(o0) | ((unsigned int)f2bf(o1) << 16);
  *(unsigned int*)(out + (size_t)node*128 + ch) = packed;
}

__global__ __launch_bounds__(256) void k_edge64(
  const unsigned short* __restrict__ xl, const float* __restrict__ xr,
  const int* __restrict__ rowptr, const uint2* __restrict__ csr,
  const float* __restrict__ We, const float* __restrict__ att,
  const float* __restrict__ bias, void* __restrict__ out, int n, int ET,
  const int* __restrict__ flag)
{
  int wid = threadIdx.x >> 6;
  int lane = threadIdx.x & 63;
  int node = blockIdx.x*4 + wid;
  if (node >= n) return;
  float we0 = We[lane];
  float at0 = att[lane];          // pre-scaled by log2e
  float fxr0 = xr[(size_t)node*64 + lane];
  const unsigned short* xlc = xl + lane;
  int beg = rowptr[node], end = rowptr[node+1];
  if (beg < 0) beg = 0;
  if (end > ET) end = ET;
  float m = -1e30f, l = 0.f, a0 = 0.f;

  for (int base = beg; base < end; base += 64){
    int idx = base + lane;
    int   sv = 0; float wv = 0.f;
    if (idx < end){
      uint2 pk = csr[idx];
      sv = (int)pk.x;
      wv = __builtin_bit_cast(float, pk.y);
    }
    if ((unsigned)sv >= (unsigned)n) sv = 0;
    int c = end - base; if (c > 64) c = 64;
    int i = 0;
    for (; i + 8 <= c; i += 8){
      float x[8], w[8], pp[8];
      #pragma unroll
      for (int j = 0; j < 8; j++){
        int s = rl_i(sv, i + j);
        w[j] = rl_f(wv, i + j);
        x[j] = bf2f(xlc[(size_t)s*64]);
      }
      #pragma unroll
      for (int j = 0; j < 8; j++){
        float t = x[j] + fxr0 + w[j]*we0;
        t = fmaxf(t, 0.2f*t);
        pp[j] = sum64(t*at0);
      }
      float mx = fmaxf(fmaxf(fmaxf(pp[0], pp[1]), fmaxf(pp[2], pp[3])),
                       fmaxf(fmaxf(pp[4], pp[5]), fmaxf(pp[6], pp[7])));
      float nm = fmaxf(m, mx);
      float sc = exp2f(m - nm);
      float el = 0.f, ea = 0.f;
      #pragma unroll
      for (int j = 0; j < 8; j++){
        float e = exp2f(pp[j] - nm);
        el += e;
        ea += e*x[j];
      }
      l  = l*sc  + el;
      a0 = a0*sc + ea;
      m = nm;
    }
    for (; i < c; i++){
      int   s = rl_i(sv, i);
      float w = rl_f(wv, i);
      float x0 = bf2f(xlc[(size_t)s*64]);
      float t0 = x0 + fxr0 + w*we0;
      t0 = fmaxf(t0, 0.2f*t0);
      float p = sum64(t0*at0);
      float nm = fmaxf(m, p);
      float sc = exp2f(m - nm);
      float pe = exp2f(p - nm);
      l  = l*sc  + pe;
      a0 = a0*sc + pe*x0;
      m = nm;
    }
  }
  float inv = 1.0f / (l + 1e-16f);
  float res = a0*inv + bias[lane];
  size_t oi = (size_t)node*64 + lane;
  if (flag[0]) ((float*)out)[oi] = res;
  else         ((unsigned short*)out)[oi] = f2bf(res);
}

// ---------------- host ----------------

extern "C" void kernel_launch(void* const* d_in, const int* in_sizes, int n_in,
                              void* d_out, int out_size, void* d_ws, size_t ws_size,
                              hipStream_t stream)
{
  (void)n_in; (void)out_size; (void)ws_size;
  const void* x   = d_in[0];
  const int*  ei  = (const int*)d_in[1];
  const void* ew  = d_in[2];

  const int N = in_sizes[0] / 128;
  const int E = in_sizes[2];
  const int ET = E + N;
  const int nB = (N + 255) / 256;

  char* p = (char*)d_ws;
  size_t off = 0;
  auto carve = [&](size_t bytes)->void* {
    void* r = p + off;
    off = (off + bytes + 255) & ~(size_t)255;
    return r;
  };
  int*            flag    = (int*)carve(4);
  int*            cnt     = (int*)carve((size_t)N*4);
  int*            rowptr  = (int*)carve((size_t)(N+1)*4);
  int*            bsum    = (int*)carve((size_t)nB*4);
  int*            boff    = (int*)carve((size_t)nB*4);
  int*            rank    = (int*)carve((size_t)E*4);
  uint2*          csr     = (uint2*)carve((size_t)ET*8);
  float*          prm     = (float*)carve(15*128*4);
  unsigned short* WT0l    = (unsigned short*)carve(128*128*2);
  unsigned short* WT0r    = (unsigned short*)carve(128*128*2);
  unsigned short* WT1l    = (unsigned short*)carve(128*128*2);
  unsigned short* WT1r    = (unsigned short*)carve(128*128*2);
  unsigned short* WT2l    = (unsigned short*)carve(128*64*2);
  unsigned short* WT2r    = (unsigned short*)carve(128*64*2);
  unsigned short* xc      = (unsigned short*)carve((size_t)N*128*2);
  unsigned short* xlb16   = (unsigned short*)carve((size_t)N*128*2);
  float*          xrb     = (float*)carve((size_t)N*128*4);
  unsigned short* hb      = (unsigned short*)carve((size_t)N*128*2);

  float* bl0c = prm + 0*128;  float* br0c = prm + 1*128;
  float* We0c = prm + 2*128;  float* at0c = prm + 3*128;  float* bi0c = prm + 4*128;
  float* bl1c = prm + 5*128;  float* br1c = prm + 6*128;
  float* We1c = prm + 7*128;  float* at1c = prm + 8*128;  float* bi1c = prm + 9*128;
  float* bl2c = prm + 10*128; float* br2c = prm + 11*128;
  float* We2c = prm + 12*128; float* at2c = prm + 13*128; float* bi2c = prm + 14*128;

  hipMemsetAsync(cnt, 0, (size_t)N*4, stream);

  k_detect<<<1, 256, 0, stream>>>((const unsigned short*)x, flag);

  const float LOG2E = 1.4426950408889634f;
  ParamTab pt;
  {
    const void* srcs[15] = { d_in[4], d_in[6], d_in[7], d_in[8], d_in[9],
                             d_in[11], d_in[13], d_in[14], d_in[15], d_in[16],
                             d_in[18], d_in[20], d_in[21], d_in[22], d_in[23] };
    float* dsts[15] = { bl0c, br0c, We0c, at0c, bi0c,
                        bl1c, br1c, We1c, at1c, bi1c,
                        bl2c, br2c, We2c, at2c, bi2c };
    int ns[15] = {128,128,128,128,128, 128,128,128,128,128, 64,64,64,64,64};
    for (int i = 0; i < 15; i++){
      pt.src[i] = srcs[i]; pt.dst[i] = dsts[i]; pt.n[i] = ns[i];
      pt.scale[i] = (i == 3 || i == 8 || i == 13) ? LOG2E : 1.0f;  // att slots
    }
  }
  k_canon_params<<<15, 128, 0, stream>>>(pt, flag);
  k_canon_bf16v<<<(((size_t)N*128/4)+255)/256, 256, 0, stream>>>(x, xc, N*128/4, flag);

  WTab wt;
  {
    const void* srcs[6] = { d_in[3], d_in[5], d_in[10], d_in[12], d_in[17], d_in[19] };
    unsigned short* dsts[6] = { WT0l, WT0r, WT1l, WT1r, WT2l, WT2r };
    int Ms[6] = {128, 128, 128, 128, 64, 64};
    for (int i = 0; i < 6; i++){ wt.src[i] = srcs[i]; wt.dst[i] = dsts[i]; wt.M[i] = Ms[i]; }
  }
  k_canonT<<<dim3(64, 6), 256, 0, stream>>>(wt, flag);

  // graph build: 1 atomic/edge (hist+rank), then atomic-free scatter
  k_hist <<<(E+255)/256, 256, 0, stream>>>(ei, cnt, rank, E, N);
  k_scan1<<<nB, 256, 0, stream>>>(cnt, bsum, N);
  k_scan2<<<1, 1024, 0, stream>>>(bsum, boff, nB);
  k_scan3<<<nB, 256, 0, stream>>>(cnt, boff, rowptr, N);
  k_scatter<<<(E+255)/256, 256, 0, stream>>>(ei, ew, rank, rowptr, csr, E, N, ET, flag);
  k_selfw<<<nB, 256, 0, stream>>>(rowptr, csr, N);

  const int rowBlocks = (N + 63) / 64;

  // layer 0
  k_gemm2<128><<<dim3(rowBlocks, 2), 64, 0, stream>>>(xc, WT0l, WT0r, bl0c, br0c, xlb16, xrb, N);
  k_edge128<<<(N+3)/4, 256, 0, stream>>>(xlb16, xrb, rowptr, csr, We0c, at0c, bi0c, hb, N, ET);

  // layer 1
  k_gemm2<128><<<dim3(rowBlocks, 2), 64, 0, stream>>>(hb, WT1l, WT1r, bl1c, br1c, xlb16, xrb, N);
  k_edge128<<<(N+3)/4, 256, 0, stream>>>(xlb16, xrb, rowptr, csr, We1c, at1c, bi1c, hb, N, ET);

  // layer 2
  k_gemm2<64><<<dim3(rowBlocks, 2), 64, 0, stream>>>(hb, WT2l, WT2r, bl2c, br2c, xlb16, xrb, N);
  k_edge64<<<(N+3)/4, 256, 0, stream>>>(xlb16, xrb, rowptr, csr, We2c, at2c, bi2c,
                                        d_out, N, ET, flag);
}

// Round 11
// 465.187 us; speedup vs baseline: 1.8964x; 1.0272x over previous
//
#include <hip/hip_runtime.h>
#include <cstdint>
#include <cstddef>

typedef __bf16 bf16x8 __attribute__((ext_vector_type(8)));
typedef float f32x4 __attribute__((ext_vector_type(4)));

__device__ __forceinline__ float bf2f(unsigned short u){
  unsigned int x = ((unsigned int)u) << 16;
  return __builtin_bit_cast(float, x);
}
__device__ __forceinline__ unsigned short f2bf(float f){
  unsigned int x = __builtin_bit_cast(unsigned int, f);
  x += 0x7fffu + ((x >> 16) & 1u);
  return (unsigned short)(x >> 16);
}

// ---- DS-free cross-lane helpers: readlane (VALU) + DPP reductions ----
__device__ __forceinline__ int rl_i(int v, int l){ return __builtin_amdgcn_readlane(v, l); }
__device__ __forceinline__ float rl_f(float v, int l){
  return __builtin_bit_cast(float, __builtin_amdgcn_readlane(__builtin_bit_cast(int, v), l));
}
template<int C> __device__ __forceinline__ float dpp_add(float x){
  int y = __builtin_amdgcn_update_dpp(0, __builtin_bit_cast(int, x), C, 0xF, 0xF, true);
  return x + __builtin_bit_cast(float, y);
}
__device__ __forceinline__ float sum16(float x){
  x = dpp_add<0xB1>(x);    // quad_perm [1,0,3,2]
  x = dpp_add<0x4E>(x);    // quad_perm [2,3,0,1]
  x = dpp_add<0x124>(x);   // row_ror:4
  x = dpp_add<0x128>(x);   // row_ror:8
  return x;
}
__device__ __forceinline__ float sum64(float x){
  x = sum16(x);
  x = dpp_add<0x142>(x);   // row_bcast15
  x = dpp_add<0x143>(x);   // row_bcast31
  return rl_f(x, 63);
}

__device__ __forceinline__ float load_w(const void* ew, int e, int f){
  return f ? ((const float*)ew)[e] : bf2f(((const unsigned short*)ew)[e]);
}

// ---------------- mega canon kernel ----------------
// One launch: per-block dtype flag (256-short probe of x), param canon,
// weight transpose canon, x->bf16 canon, cnt zeroing. Block ranges:
//   [0]                 params + flag store
//   [1, 321)            weight tensors (64,64,64,64,32,32 blocks)
//   [321, 321+xB)       x canon (ushort4 granules)
//   [321+xB, ...)       cnt zero (int4 granules)

struct MegaArgs {
  const void* psrc[15]; float* pdst[15]; int pn[15]; float pscale[15];
  const void* wsrc[6]; unsigned short* wdst[6]; int wM[6];
  const void* x; unsigned short* xc; int n4;
  int* cnt; int nz4;
  int* flag;
};

__global__ __launch_bounds__(256) void k_mega(MegaArgs a){
  __shared__ int sf;
  if (threadIdx.x == 0) sf = 0;
  __syncthreads();
  {
    unsigned short u = ((const unsigned short*)a.x)[threadIdx.x];
    int expo = (u >> 7) & 0xFF;
    if (expo >= 0xC0) atomicOr(&sf, 1);
  }
  __syncthreads();
  int f = sf;
  int b = blockIdx.x;

  if (b == 0){
    if (threadIdx.x == 0) a.flag[0] = f;
    for (int t = 0; t < 15; t++){
      int i = threadIdx.x;
      if (i < a.pn[t]){
        float v = f ? ((const float*)a.psrc[t])[i]
                    : bf2f(((const unsigned short*)a.psrc[t])[i]);
        a.pdst[t][i] = v * a.pscale[t];
      }
    }
    return;
  }
  b -= 1;
  if (b < 320){
    int t, base;
    if      (b <  64){ t = 0; base = b;       }
    else if (b < 128){ t = 1; base = b - 64;  }
    else if (b < 192){ t = 2; base = b - 128; }
    else if (b < 256){ t = 3; base = b - 192; }
    else if (b < 288){ t = 4; base = b - 256; }
    else             { t = 5; base = b - 288; }
    int M = a.wM[t];
    int idx = base*256 + threadIdx.x;
    if (idx < 128*M){
      int k = idx / M, m2 = idx % M;
      unsigned short v = f ? f2bf(((const float*)a.wsrc[t])[idx])
                           : ((const unsigned short*)a.wsrc[t])[idx];
      a.wdst[t][m2*128 + k] = v;
    }
    return;
  }
  b -= 320;
  int xB = (a.n4 + 255) / 256;
  if (b < xB){
    int i = b*256 + threadIdx.x;
    if (i < a.n4){
      if (f){
        float4 v = ((const float4*)a.x)[i];
        ushort4 o;
        o.x = f2bf(v.x); o.y = f2bf(v.y); o.z = f2bf(v.z); o.w = f2bf(v.w);
        ((ushort4*)a.xc)[i] = o;
      } else {
        ((ushort4*)a.xc)[i] = ((const ushort4*)a.x)[i];
      }
    }
    return;
  }
  b -= xB;
  int i = b*256 + threadIdx.x;
  if (i < a.nz4) ((int4*)a.cnt)[i] = make_int4(0, 0, 0, 0);
}

// ---------------- graph build ----------------

__global__ void k_hist(const int* __restrict__ ei, int* __restrict__ cnt,
                       int* __restrict__ rank, int E, int n){
  int e = blockIdx.x*256 + threadIdx.x;
  if (e < E){
    int d = ei[E + e];
    int r = 0;
    if ((unsigned)d < (unsigned)n) r = atomicAdd(&cnt[d], 1);
    rank[e] = r;
  }
}

__global__ void k_scan1(const int* __restrict__ cnt, int* __restrict__ bsum, int n){
  int i = blockIdx.x*256 + threadIdx.x;
  int lane = threadIdx.x & 63, w = threadIdx.x >> 6;
  int v = (i < n) ? cnt[i] + 1 : 0;
  for (int off = 32; off; off >>= 1) v += __shfl_down(v, off);
  __shared__ int ws[4];
  if (lane == 0) ws[w] = v;
  __syncthreads();
  if (threadIdx.x == 0) bsum[blockIdx.x] = ws[0] + ws[1] + ws[2] + ws[3];
}

// fused scan phases 2+3: each block reduces bsum[0..b) inline, then scans its chunk
__global__ void k_scan3(const int* __restrict__ cnt, const int* __restrict__ bsum,
                        int* __restrict__ rowptr, int n, int nB){
  int b = blockIdx.x, tid = threadIdx.x;
  int lane = tid & 63, w = tid >> 6;
  __shared__ int ws[4];
  __shared__ int sboff;

  // block offset: sum of bsum[j] for j < b
  int part = 0;
  for (int t = tid; t < b; t += 256) part += bsum[t];
  for (int off = 32; off; off >>= 1) part += __shfl_down(part, off);
  if (lane == 0) ws[w] = part;
  __syncthreads();
  if (tid == 0) sboff = ws[0] + ws[1] + ws[2] + ws[3];
  __syncthreads();
  int boff = sboff;
  __syncthreads();

  int i = b*256 + tid;
  int v = (i < n) ? cnt[i] + 1 : 0;
  int sv = v;
  for (int off = 1; off < 64; off <<= 1){
    int t = __shfl_up(sv, off);
    if (lane >= off) sv += t;
  }
  if (lane == 63) ws[w] = sv;
  __syncthreads();
  if (tid == 0){
    int acc = 0;
    for (int k = 0; k < 4; k++){ int t = ws[k]; ws[k] = acc; acc += t; }
  }
  __syncthreads();
  if (i < n) rowptr[i + 1] = boff + ws[w] + sv;
  if (i == 0) rowptr[0] = 0;
  (void)nB;
}

// ATOMIC-FREE scatter: pos = rowptr[d] + rank[e]; one packed 8B store per edge
__global__ void k_scatter(const int* __restrict__ ei, const void* __restrict__ ew,
                          const int* __restrict__ rank, const int* __restrict__ rowptr,
                          uint2* __restrict__ csr,
                          int E, int n, int ET, const int* __restrict__ flag){
  int e = blockIdx.x*256 + threadIdx.x;
  if (e < E){
    int s = ei[e], d = ei[E + e];
    if ((unsigned)d < (unsigned)n){
      int pos = rowptr[d] + rank[e];
      if ((unsigned)pos < (unsigned)ET){
        float w = load_w(ew, e, flag[0]);
        csr[pos] = make_uint2((unsigned)s, __builtin_bit_cast(unsigned, w));
      }
    }
  }
}

// per-node: sum weights over own segment (atomic-free), write self-loop in last slot
__global__ void k_selfw(const int* __restrict__ rowptr, uint2* __restrict__ csr, int n){
  int i = blockIdx.x*256 + threadIdx.x;
  if (i < n){
    int beg = rowptr[i], endv = rowptr[i+1];
    int deg = endv - 1 - beg;
    float ws = 0.f;
    for (int j = beg; j < endv - 1; j++)
      ws += __builtin_bit_cast(float, csr[j].y);
    float w = ws / fmaxf((float)deg, 1.0f);
    csr[endv - 1] = make_uint2((unsigned)i, __builtin_bit_cast(unsigned, w));
  }
}

// ---------------- GEMM: xl (bf16 out) and xr (f32 out) in one launch ----------------

template<int NC>
__global__ __launch_bounds__(64) void k_gemm2(
  const unsigned short* __restrict__ A,
  const unsigned short* __restrict__ WTl, const unsigned short* __restrict__ WTr,
  const float* __restrict__ bl, const float* __restrict__ br,
  unsigned short* __restrict__ outL, float* __restrict__ outR,
  int nrows)
{
  constexpr int CT = NC / 16;
  int lane = threadIdx.x;
  int q = lane >> 4, rr = lane & 15;
  int r0 = blockIdx.x * 64;
  bool isR = blockIdx.y == 1;
  const unsigned short* WT = isR ? WTr : WTl;
  const float* bia         = isR ? br  : bl;

  f32x4 acc[4][CT];
  for (int a = 0; a < 4; a++)
    for (int b = 0; b < CT; b++)
      acc[a][b] = (f32x4){0.f, 0.f, 0.f, 0.f};

  for (int kc = 0; kc < 4; kc++){
    bf16x8 af[4], bfr[CT];
    #pragma unroll
    for (int rt = 0; rt < 4; rt++){
      int row = r0 + rt*16 + rr;
      if (row >= nrows) row = nrows - 1;
      af[rt] = *(const bf16x8*)(A + (size_t)row*128 + kc*32 + q*8);
    }
    #pragma unroll
    for (int ct = 0; ct < CT; ct++)
      bfr[ct] = *(const bf16x8*)(WT + (size_t)(ct*16 + rr)*128 + kc*32 + q*8);
    #pragma unroll
    for (int rt = 0; rt < 4; rt++)
      #pragma unroll
      for (int ct = 0; ct < CT; ct++)
        acc[rt][ct] = __builtin_amdgcn_mfma_f32_16x16x32_bf16(af[rt], bfr[ct], acc[rt][ct], 0, 0, 0);
  }

  // C/D layout: col = lane&15, row = (lane>>4)*4 + reg
  #pragma unroll
  for (int ct = 0; ct < CT; ct++){
    int col = ct*16 + rr;
    float bv = bia[col];
    #pragma unroll
    for (int rt = 0; rt < 4; rt++){
      #pragma unroll
      for (int t = 0; t < 4; t++){
        int row = r0 + rt*16 + q*4 + t;
        if (row < nrows){
          float v = acc[rt][ct][t] + bv;
          if (isR) outR[(size_t)row*NC + col] = v;
          else     outL[(size_t)row*NC + col] = f2bf(v);
        }
      }
    }
  }
}

// ---------------- fused edge scoring + online-softmax aggregation ----------------
// DS-free (readlane + DPP); scalar channel math; exp2 softmax (att pre-scaled
// by log2e); 8-wide unroll for gather MLP. [round-10 proven bodies]

__global__ __launch_bounds__(256) void k_edge128(
  const unsigned short* __restrict__ xl, const float* __restrict__ xr,
  const int* __restrict__ rowptr, const uint2* __restrict__ csr,
  const float* __restrict__ We, const float* __restrict__ att,
  const float* __restrict__ bias, unsigned short* __restrict__ out, int n, int ET)
{
  int wid = threadIdx.x >> 6;
  int lane = threadIdx.x & 63;
  int node = blockIdx.x*4 + wid;
  if (node >= n) return;
  int ch = lane*2;
  float we0 = We[ch],  we1 = We[ch+1];
  float at0 = att[ch], at1 = att[ch+1];   // pre-scaled by log2e
  float2 xrv = *(const float2*)(xr + (size_t)node*128 + ch);
  float fxr0 = xrv.x, fxr1 = xrv.y;
  const unsigned short* xlc = xl + ch;
  int beg = rowptr[node], end = rowptr[node+1];
  if (beg < 0) beg = 0;
  if (end > ET) end = ET;
  float m = -1e30f, l = 0.f, a0 = 0.f, a1 = 0.f;

  for (int base = beg; base < end; base += 64){
    int idx = base + lane;
    int   sv = 0; float wv = 0.f;
    if (idx < end){
      uint2 pk = csr[idx];
      sv = (int)pk.x;
      wv = __builtin_bit_cast(float, pk.y);
    }
    if ((unsigned)sv >= (unsigned)n) sv = 0;
    int c = end - base; if (c > 64) c = 64;
    int i = 0;
    for (; i + 8 <= c; i += 8){
      unsigned int u[8]; float w[8];
      #pragma unroll
      for (int j = 0; j < 8; j++){
        int s = rl_i(sv, i + j);
        w[j] = rl_f(wv, i + j);
        u[j] = *(const unsigned int*)(xlc + (size_t)s*128);
      }
      float vx[8], vy[8], pp[8];
      #pragma unroll
      for (int j = 0; j < 8; j++){
        vx[j] = __builtin_bit_cast(float, u[j] << 16);
        vy[j] = __builtin_bit_cast(float, u[j] & 0xffff0000u);
        float t0 = vx[j] + fxr0 + w[j]*we0;
        float t1 = vy[j] + fxr1 + w[j]*we1;
        t0 = fmaxf(t0, 0.2f*t0);
        t1 = fmaxf(t1, 0.2f*t1);
        pp[j] = sum16(t0*at0 + t1*at1);
      }
      float mx = fmaxf(fmaxf(fmaxf(pp[0], pp[1]), fmaxf(pp[2], pp[3])),
                       fmaxf(fmaxf(pp[4], pp[5]), fmaxf(pp[6], pp[7])));
      float nm = fmaxf(m, mx);
      float sc = exp2f(m - nm);
      float el = 0.f, ea0 = 0.f, ea1 = 0.f;
      #pragma unroll
      for (int j = 0; j < 8; j++){
        float e = exp2f(pp[j] - nm);
        el  += e;
        ea0 += e*vx[j];
        ea1 += e*vy[j];
      }
      l  = l*sc  + el;
      a0 = a0*sc + ea0;
      a1 = a1*sc + ea1;
      m = nm;
    }
    for (; i < c; i++){
      int   s = rl_i(sv, i);
      float w = rl_f(wv, i);
      unsigned int u = *(const unsigned int*)(xlc + (size_t)s*128);
      float x0 = __builtin_bit_cast(float, u << 16);
      float x1 = __builtin_bit_cast(float, u & 0xffff0000u);
      float t0 = x0 + fxr0 + w*we0;
      float t1 = x1 + fxr1 + w*we1;
      t0 = fmaxf(t0, 0.2f*t0);
      t1 = fmaxf(t1, 0.2f*t1);
      float p = sum16(t0*at0 + t1*at1);
      float nm = fmaxf(m, p);
      float sc = exp2f(m - nm);
      float pe = exp2f(p - nm);
      l  = l*sc  + pe;
      a0 = a0*sc + pe*x0;
      a1 = a1*sc + pe*x1;
      m = nm;
    }
  }
  float inv = 1.0f / (l + 1e-16f);
  float o0 = a0*inv + bias[ch];
  float o1 = a1*inv + bias[ch+1];
  o0 = o0 > 0.f ? o0 : (__expf(o0) - 1.0f);   // ELU (layers 0,1)
  o1 = o1 > 0.f ? o1 : (__expf(o1) - 1.0f);
  unsigned int packed = (unsigned int)f2bf(o0) | ((unsigned int)f2bf(o1) << 16);
  *(unsigned int*)(out + (size_t)node*128 + ch) = packed;
}

__global__ __launch_bounds__(256) void k_edge64(
  const unsigned short* __restrict__ xl, const float* __restrict__ xr,
  const int* __restrict__ rowptr, const uint2* __restrict__ csr,
  const float* __restrict__ We, const float* __restrict__ att,
  const float* __restrict__ bias, void* __restrict__ out, int n, int ET,
  const int* __restrict__ flag)
{
  int wid = threadIdx.x >> 6;
  int lane = threadIdx.x & 63;
  int node = blockIdx.x*4 + wid;
  if (node >= n) return;
  float we0 = We[lane];
  float at0 = att[lane];          // pre-scaled by log2e
  float fxr0 = xr[(size_t)node*64 + lane];
  const unsigned short* xlc = xl + lane;
  int beg = rowptr[node], end = rowptr[node+1];
  if (beg < 0) beg = 0;
  if (end > ET) end = ET;
  float m = -1e30f, l = 0.f, a0 = 0.f;

  for (int base = beg; base < end; base += 64){
    int idx = base + lane;
    int   sv = 0; float wv = 0.f;
    if (idx < end){
      uint2 pk = csr[idx];
      sv = (int)pk.x;
      wv = __builtin_bit_cast(float, pk.y);
    }
    if ((unsigned)sv >= (unsigned)n) sv = 0;
    int c = end - base; if (c > 64) c = 64;
    int i = 0;
    for (; i + 8 <= c; i += 8){
      float x[8], w[8], pp[8];
      #pragma unroll
      for (int j = 0; j < 8; j++){
        int s = rl_i(sv, i + j);
        w[j] = rl_f(wv, i + j);
        x[j] = bf2f(xlc[(size_t)s*64]);
      }
      #pragma unroll
      for (int j = 0; j < 8; j++){
        float t = x[j] + fxr0 + w[j]*we0;
        t = fmaxf(t, 0.2f*t);
        pp[j] = sum64(t*at0);
      }
      float mx = fmaxf(fmaxf(fmaxf(pp[0], pp[1]), fmaxf(pp[2], pp[3])),
                       fmaxf(fmaxf(pp[4], pp[5]), fmaxf(pp[6], pp[7])));
      float nm = fmaxf(m, mx);
      float sc = exp2f(m - nm);
      float el = 0.f, ea = 0.f;
      #pragma unroll
      for (int j = 0; j < 8; j++){
        float e = exp2f(pp[j] - nm);
        el += e;
        ea += e*x[j];
      }
      l  = l*sc  + el;
      a0 = a0*sc + ea;
      m = nm;
    }
    for (; i < c; i++){
      int   s = rl_i(sv, i);
      float w = rl_f(wv, i);
      float x0 = bf2f(xlc[(size_t)s*64]);
      float t0 = x0 + fxr0 + w*we0;
      t0 = fmaxf(t0, 0.2f*t0);
      float p = sum64(t0*at0);
      float nm = fmaxf(m, p);
      float sc = exp2f(m - nm);
      float pe = exp2f(p - nm);
      l  = l*sc  + pe;
      a0 = a0*sc + pe*x0;
      m = nm;
    }
  }
  float inv = 1.0f / (l + 1e-16f);
  float res = a0*inv + bias[lane];
  size_t oi = (size_t)node*64 + lane;
  if (flag[0]) ((float*)out)[oi] = res;
  else         ((unsigned short*)out)[oi] = f2bf(res);
}

// ---------------- host ----------------

extern "C" void kernel_launch(void* const* d_in, const int* in_sizes, int n_in,
                              void* d_out, int out_size, void* d_ws, size_t ws_size,
                              hipStream_t stream)
{
  (void)n_in; (void)out_size; (void)ws_size;
  const void* x   = d_in[0];
  const int*  ei  = (const int*)d_in[1];
  const void* ew  = d_in[2];

  const int N = in_sizes[0] / 128;
  const int E = in_sizes[2];
  const int ET = E + N;
  const int nB = (N + 255) / 256;

  char* p = (char*)d_ws;
  size_t off = 0;
  auto carve = [&](size_t bytes)->void* {
    void* r = p + off;
    off = (off + bytes + 255) & ~(size_t)255;
    return r;
  };
  int*            flag    = (int*)carve(4);
  int*            cnt     = (int*)carve((size_t)((N+3)/4)*16);
  int*            rowptr  = (int*)carve((size_t)(N+1)*4);
  int*            bsum    = (int*)carve((size_t)nB*4);
  int*            rank    = (int*)carve((size_t)E*4);
  uint2*          csr     = (uint2*)carve((size_t)ET*8);
  float*          prm     = (float*)carve(15*128*4);
  unsigned short* WT0l    = (unsigned short*)carve(128*128*2);
  unsigned short* WT0r    = (unsigned short*)carve(128*128*2);
  unsigned short* WT1l    = (unsigned short*)carve(128*128*2);
  unsigned short* WT1r    = (unsigned short*)carve(128*128*2);
  unsigned short* WT2l    = (unsigned short*)carve(128*64*2);
  unsigned short* WT2r    = (unsigned short*)carve(128*64*2);
  unsigned short* xc      = (unsigned short*)carve((size_t)N*128*2);
  unsigned short* xlb16   = (unsigned short*)carve((size_t)N*128*2);
  float*          xrb     = (float*)carve((size_t)N*128*4);
  unsigned short* hb      = (unsigned short*)carve((size_t)N*128*2);

  float* bl0c = prm + 0*128;  float* br0c = prm + 1*128;
  float* We0c = prm + 2*128;  float* at0c = prm + 3*128;  float* bi0c = prm + 4*128;
  float* bl1c = prm + 5*128;  float* br1c = prm + 6*128;
  float* We1c = prm + 7*128;  float* at1c = prm + 8*128;  float* bi1c = prm + 9*128;
  float* bl2c = prm + 10*128; float* br2c = prm + 11*128;
  float* We2c = prm + 12*128; float* at2c = prm + 13*128; float* bi2c = prm + 14*128;

  const float LOG2E = 1.4426950408889634f;
  MegaArgs ma;
  {
    const void* srcs[15] = { d_in[4], d_in[6], d_in[7], d_in[8], d_in[9],
                             d_in[11], d_in[13], d_in[14], d_in[15], d_in[16],
                             d_in[18], d_in[20], d_in[21], d_in[22], d_in[23] };
    float* dsts[15] = { bl0c, br0c, We0c, at0c, bi0c,
                        bl1c, br1c, We1c, at1c, bi1c,
                        bl2c, br2c, We2c, at2c, bi2c };
    int ns[15] = {128,128,128,128,128, 128,128,128,128,128, 64,64,64,64,64};
    for (int i = 0; i < 15; i++){
      ma.psrc[i] = srcs[i]; ma.pdst[i] = dsts[i]; ma.pn[i] = ns[i];
      ma.pscale[i] = (i == 3 || i == 8 || i == 13) ? LOG2E : 1.0f;  // att slots
    }
    const void* wsrcs[6] = { d_in[3], d_in[5], d_in[10], d_in[12], d_in[17], d_in[19] };
    unsigned short* wdsts[6] = { WT0l, WT0r, WT1l, WT1r, WT2l, WT2r };
    int Ms[6] = {128, 128, 128, 128, 64, 64};
    for (int i = 0; i < 6; i++){ ma.wsrc[i] = wsrcs[i]; ma.wdst[i] = wdsts[i]; ma.wM[i] = Ms[i]; }
    ma.x = x; ma.xc = xc; ma.n4 = N*32;
    ma.cnt = cnt; ma.nz4 = (N + 3) / 4;
    ma.flag = flag;
  }
  int xB = (ma.n4 + 255) / 256;
  int zB = (ma.nz4 + 255) / 256;
  k_mega<<<1 + 320 + xB + zB, 256, 0, stream>>>(ma);

  // graph build: 1 atomic/edge (hist+rank), 2-launch scan, atomic-free scatter
  k_hist <<<(E+255)/256, 256, 0, stream>>>(ei, cnt, rank, E, N);
  k_scan1<<<nB, 256, 0, stream>>>(cnt, bsum, N);
  k_scan3<<<nB, 256, 0, stream>>>(cnt, bsum, rowptr, N, nB);
  k_scatter<<<(E+255)/256, 256, 0, stream>>>(ei, ew, rank, rowptr, csr, E, N, ET, flag);
  k_selfw<<<nB, 256, 0, stream>>>(rowptr, csr, N);

  const int rowBlocks = (N + 63) / 64;

  // layer 0
  k_gemm2<128><<<dim3(rowBlocks, 2), 64, 0, stream>>>(xc, WT0l, WT0r, bl0c, br0c, xlb16, xrb, N);
  k_edge128<<<(N+3)/4, 256, 0, stream>>>(xlb16, xrb, rowptr, csr, We0c, at0c, bi0c, hb, N, ET);

  // layer 1
  k_gemm2<128><<<dim3(rowBlocks, 2), 64, 0, stream>>>(hb, WT1l, WT1r, bl1c, br1c, xlb16, xrb, N);
  k_edge128<<<(N+3)/4, 256, 0, stream>>>(xlb16, xrb, rowptr, csr, We1c, at1c, bi1c, hb, N, ET);

  // layer 2
  k_gemm2<64><<<dim3(rowBlocks, 2), 64, 0, stream>>>(hb, WT2l, WT2r, bl2c, br2c, xlb16, xrb, N);
  k_edge64<<<(N+3)/4, 256, 0, stream>>>(xlb16, xrb, rowptr, csr, We2c, at2c, bi2c,
                                        d_out, N, ET, flag);
}